// Round 9
// baseline (206.426 us; speedup 1.0000x reference)
//
#include <hip/hip_runtime.h>

#define N_NODES 50000
#define N_EDGES 800000
#define HEADS 8
#define NEG_SLOPE 0.2f
#define EPS 1e-16f
#define NBUCK 782            // ceil(50000/64) buckets of 64 dst nodes
#define BNODES 64
#define BCAP 1312            // bucket capacity (load ~Poisson(1023); +9 sigma)
#define BINB 250             // bin blocks
#define EPB 3200             // 800000 / 250 edges per bin block
#define LOG2E 1.4426950408889634f

// bf16x2 pack/unpack (RNE), exact unpack
__device__ inline unsigned int f2_to_bf2(float a, float b) {
    unsigned int ua = __float_as_uint(a);
    unsigned int ub = __float_as_uint(b);
    ua += 0x7fff + ((ua >> 16) & 1);
    ub += 0x7fff + ((ub >> 16) & 1);
    return (ua >> 16) | (ub & 0xffff0000u);
}
__device__ inline float2 bf2_to_f2(unsigned int u) {
    return make_float2(__uint_as_float(u << 16),
                       __uint_as_float(u & 0xffff0000u));
}

// ---------------------------------------------------------------------------
// Kernel 1: x@W GEMM with ZERO LDS. r6-r8 lesson: the 32KB LDS footprint
// capped gemm blocks at ~16 waves/CU and no ILP/TLP lever moved the stall.
// The block's x working set (64 rows x 512B = 32KB) fits L1 exactly; wave
// x-loads are 2-address broadcasts and W-loads one 512B segment, so L1
// serves everything. No LDS, no barriers -> 4 blocks/CU (thread-limited),
// 32 waves/CU, 8/SIMD. Ascending-k accumulation order preserved.
// ---------------------------------------------------------------------------
__global__ __launch_bounds__(512) void k_gemm(const float* __restrict__ x,
                                              const float* __restrict__ W,
                                              const float* __restrict__ att_s,
                                              const float* __restrict__ att_d,
                                              unsigned int* __restrict__ h_bf,
                                              float* __restrict__ asrc,
                                              float* __restrict__ adst) {
    const int tid = threadIdx.x;
    const int row0 = blockIdx.x * 64;
    const int colg = tid & 31;        // W float4-column
    const int rowg = tid >> 5;        // 0..15, 4 rows each

    // clamped float4-row bases for safe loads (stores are guarded)
    int rw[4];
#pragma unroll
    for (int r = 0; r < 4; ++r) {
        const int row = row0 + rowg * 4 + r;
        rw[r] = ((row < N_NODES) ? row : (N_NODES - 1)) * 32;
    }

    float acc[4][4];
#pragma unroll
    for (int r = 0; r < 4; ++r)
#pragma unroll
        for (int j = 0; j < 4; ++j) acc[r][j] = 0.f;

    const float4* W4 = (const float4*)W;
    const float4* X4 = (const float4*)x;

#pragma unroll 2
    for (int k4 = 0; k4 < 32; ++k4) {           // k = 4*k4 .. 4*k4+3
        const float4 w0 = W4[(k4 * 4 + 0) * 32 + colg];
        const float4 w1 = W4[(k4 * 4 + 1) * 32 + colg];
        const float4 w2 = W4[(k4 * 4 + 2) * 32 + colg];
        const float4 w3 = W4[(k4 * 4 + 3) * 32 + colg];
        float4 xr[4];
#pragma unroll
        for (int r = 0; r < 4; ++r) xr[r] = X4[rw[r] + k4];

#pragma unroll
        for (int r = 0; r < 4; ++r) {
            const float x0 = xr[r].x, x1 = xr[r].y, x2 = xr[r].z, x3 = xr[r].w;
            // per-accumulator adds in ascending k order (bit-stable)
            acc[r][0] += x0 * w0.x; acc[r][0] += x1 * w1.x;
            acc[r][0] += x2 * w2.x; acc[r][0] += x3 * w3.x;
            acc[r][1] += x0 * w0.y; acc[r][1] += x1 * w1.y;
            acc[r][1] += x2 * w2.y; acc[r][1] += x3 * w3.y;
            acc[r][2] += x0 * w0.z; acc[r][2] += x1 * w1.z;
            acc[r][2] += x2 * w2.z; acc[r][2] += x3 * w3.z;
            acc[r][3] += x0 * w0.w; acc[r][3] += x1 * w1.w;
            acc[r][3] += x2 * w2.w; acc[r][3] += x3 * w3.w;
        }
    }

    const int hd = colg >> 2;
    const float4 asv = ((const float4*)att_s)[colg];
    const float4 adv = ((const float4*)att_d)[colg];
#pragma unroll
    for (int r = 0; r < 4; ++r) {
        const int row = row0 + rowg * 4 + r;
        float ps = acc[r][0] * asv.x + acc[r][1] * asv.y +
                   acc[r][2] * asv.z + acc[r][3] * asv.w;
        float pd = acc[r][0] * adv.x + acc[r][1] * adv.y +
                   acc[r][2] * adv.z + acc[r][3] * adv.w;
        ps += __shfl_xor(ps, 1); ps += __shfl_xor(ps, 2);
        pd += __shfl_xor(pd, 1); pd += __shfl_xor(pd, 2);
        if (row < N_NODES) {
            if ((colg & 3) == 0) {
                asrc[row * 8 + hd] = ps * LOG2E;   // pre-scale for exp2
                adst[row * 8 + hd] = pd * LOG2E;
            }
            uint2 p;
            p.x = f2_to_bf2(acc[r][0], acc[r][1]);
            p.y = f2_to_bf2(acc[r][2], acc[r][3]);
            ((uint2*)h_bf)[row * 32 + colg] = p;
        }
    }
}

// ---------------------------------------------------------------------------
// Kernel 2: edge bucket-binning (standalone again; gemm must be LDS-free).
// 250 blocks x 512 threads x 3200 edges. LDS counting sort by 64-node
// bucket, two-level shfl scan, one global atomic per (block,bucket),
// contiguous run copy-out. Record = (dst<<16)|src.
// ---------------------------------------------------------------------------
__global__ __launch_bounds__(512) void k_bin(const int* __restrict__ ei,
                                             int* __restrict__ cnt,
                                             unsigned int* __restrict__ bin) {
    __shared__ unsigned int srt[EPB];     // 12.8 KB
    __shared__ int hist[NBUCK];
    __shared__ int base[NBUCK];
    __shared__ int cur[NBUCK];
    __shared__ int gbase[NBUCK];
    __shared__ int wsum[8];
    const int tid = threadIdx.x;
    const int lane = tid & 63;
    const int wid = tid >> 6;
    const int e0 = blockIdx.x * EPB;

    for (int b = tid; b < NBUCK; b += 512) hist[b] = 0;
    __syncthreads();

    // pass 1: histogram (bucket = dst >> 6)
    for (int i = tid; i < EPB; i += 512)
        atomicAdd(&hist[ei[N_EDGES + e0 + i] >> 6], 1);
    __syncthreads();

    // exclusive scan: thread owns buckets 2t..2t+1, two-level shfl scan
    const int b2 = tid * 2;
    const int l0 = (b2     < NBUCK) ? hist[b2]     : 0;
    const int l1 = (b2 + 1 < NBUCK) ? hist[b2 + 1] : 0;
    const int tot = l0 + l1;
    int inc = tot;
#pragma unroll
    for (int off = 1; off < 64; off <<= 1) {
        const int u = __shfl_up(inc, off);
        if (lane >= off) inc += u;
    }
    if (lane == 63) wsum[wid] = inc;
    __syncthreads();
    int run = inc - tot;
    for (int w2 = 0; w2 < wid; ++w2) run += wsum[w2];
    if (b2     < NBUCK) { base[b2]     = run; cur[b2]     = run; } run += l0;
    if (b2 + 1 < NBUCK) { base[b2 + 1] = run; cur[b2 + 1] = run; }
    __syncthreads();

    // pass 2: scatter into sorted LDS
    for (int i = tid; i < EPB; i += 512) {
        const unsigned src = (unsigned)ei[e0 + i];
        const unsigned dst = (unsigned)ei[N_EDGES + e0 + i];
        const int p = atomicAdd(&cur[dst >> 6], 1);
        if ((unsigned)p < (unsigned)EPB) srt[p] = (dst << 16) | src;
    }
    __syncthreads();

    // reserve global ranges (one atomic per non-empty bucket)
    for (int b = tid; b < NBUCK; b += 512)
        gbase[b] = (hist[b] > 0) ? atomicAdd(&cnt[b], hist[b]) : 0;
    __syncthreads();

    // contiguous run copy-out
    for (int p = tid; p < EPB; p += 512) {
        const unsigned rec = srt[p];
        const int b = rec >> 22;
        if (b < NBUCK) {
            const int pos = gbase[b] + (p - base[b]);
            if ((unsigned)pos < (unsigned)BCAP)
                bin[(size_t)b * BCAP + pos] = rec;
        }
    }
}

// ---------------------------------------------------------------------------
// Kernel 3: aggregation (round-3 structure, proven ~53 us profiled). One
// block (8 waves) per bucket; counting sort; uniform clamped depth-16
// batches; producer/consumer ex via shfl.
// ---------------------------------------------------------------------------
__global__ __launch_bounds__(512) void k_aggr(const unsigned int* __restrict__ h_bf,
                                              const unsigned int* __restrict__ bin,
                                              const int* __restrict__ cnt,
                                              const float* __restrict__ asrc,
                                              const float* __restrict__ adst,
                                              const float* __restrict__ bias,
                                              float* __restrict__ out) {
    __shared__ unsigned int srt[BCAP];    // 5.2 KB
    __shared__ int hist[BNODES], base[BNODES], scn[BNODES];

    const int bkt = blockIdx.x;
    const int tid = threadIdx.x;
    const int wid = tid >> 6;
    const int lane = tid & 63;
    const int hd = lane >> 3;     // consumer head (channels lane*2, lane*2+1)
    const int eslot = lane >> 3;  // producer edge slot 0..7
    const int phead = lane & 7;   // producer head

    const int cntb = min(cnt[bkt], BCAP);
    const unsigned int* seg = bin + (size_t)bkt * BCAP;

    if (tid < BNODES) hist[tid] = 0;
    __syncthreads();

    // single pass: read seg once, rank via LDS atomic, keep in registers
    unsigned int myrec[3];
    int myrank[3];
    int nrec = 0;
    for (int i = tid; i < cntb; i += 512) {
        const unsigned rec = seg[i];
        myrank[nrec] = atomicAdd(&hist[(rec >> 16) & 63], 1);
        myrec[nrec] = rec;
        ++nrec;
    }
    __syncthreads();

    if (tid < BNODES) scn[tid] = hist[tid];
    __syncthreads();
    for (int off = 1; off < BNODES; off <<= 1) {
        int v = 0;
        if (tid < BNODES && tid >= off) v = scn[tid - off];
        __syncthreads();
        if (tid < BNODES) scn[tid] += v;
        __syncthreads();
    }
    if (tid < BNODES) base[tid] = scn[tid] - hist[tid];
    __syncthreads();

    for (int k = 0; k < nrec; ++k) {
        const unsigned rec = myrec[k];
        const int p = base[(rec >> 16) & 63] + myrank[k];
        if ((unsigned)p < (unsigned)BCAP) srt[p] = rec;
    }
    __syncthreads();

    // per-wave node processing: wave wid handles dlocal = wid, wid+8, ...
    for (int dl = wid; dl < BNODES; dl += 8) {
        const int d = bkt * BNODES + dl;
        if (d >= N_NODES) continue;
        const int jb = base[dl];
        const int jn = hist[dl];

        const float adst_h = adst[d * 8 + hd];      // consumer head
        const float adst_p = adst[d * 8 + phead];   // producer head
        const float asrc_self = asrc[d * 8 + hd];
        const float2 hdv = bf2_to_f2(h_bf[d * 64 + lane]);

        float es = asrc_self + adst_h;
        es = fmaxf(es, NEG_SLOPE * es);       // LeakyReLU, slope<1
        const float exs = exp2f(es);          // logits pre-scaled by log2e

        float2 acc = make_float2(0.f, 0.f);
        float den = 0.f;

        for (int j0 = 0; j0 < jn; j0 += 16) {
            // broadcast copies of the 16 src ids (same addr across wave: free)
            int s[16];
#pragma unroll
            for (int i = 0; i < 16; ++i) {
                const int jj = j0 + i;
                s[i] = (int)(srt[jb + ((jj < jn) ? jj : jn - 1)] & 0xffffu);
            }
            // issue all 16 row-gathers early (MLP)
            unsigned int hv[16];
#pragma unroll
            for (int i = 0; i < 16; ++i) hv[i] = h_bf[s[i] * 64 + lane];

            // producer lanes: ex for (edge eslot / eslot+8, head phead)
            const int ia = j0 + eslot;
            const int ib = ia + 8;
            const int sa = (int)(srt[jb + min(ia, jn - 1)] & 0xffffu);
            const int sb = (int)(srt[jb + min(ib, jn - 1)] & 0xffffu);
            float eA = asrc[sa * 8 + phead] + adst_p;
            float eB = asrc[sb * 8 + phead] + adst_p;
            eA = fmaxf(eA, NEG_SLOPE * eA);
            eB = fmaxf(eB, NEG_SLOPE * eB);
            const float exA = (ia < jn) ? exp2f(eA) : 0.f;
            const float exB = (ib < jn) ? exp2f(eB) : 0.f;

#pragma unroll
            for (int i = 0; i < 16; ++i) {
                // producer of (edge i, head hd) is lane ((i&7)<<3) | hd
                const float ex = __shfl((i < 8) ? exA : exB,
                                        ((i & 7) << 3) | hd, 64);
                const float2 hv2 = bf2_to_f2(hv[i]);
                acc.x += ex * hv2.x;
                acc.y += ex * hv2.y;
                den += ex;
            }
        }

        const float dtot = den + exs + EPS;
        const float2 b2 = ((const float2*)bias)[lane];
        float vx = (acc.x + exs * hdv.x) / dtot + b2.x;
        float vy = (acc.y + exs * hdv.y) / dtot + b2.y;
        vx = (vx > 0.f) ? vx : expm1f(vx);
        vy = (vy > 0.f) ? vy : expm1f(vy);
        ((float2*)out)[d * 64 + lane] = make_float2(vx, vy);
    }
}

extern "C" void kernel_launch(void* const* d_in, const int* in_sizes, int n_in,
                              void* d_out, int out_size, void* d_ws, size_t ws_size,
                              hipStream_t stream) {
    const float* x     = (const float*)d_in[0];
    const int*   ei    = (const int*)d_in[1];
    const float* W     = (const float*)d_in[2];
    const float* att_s = (const float*)d_in[3];
    const float* att_d = (const float*)d_in[4];
    const float* bias  = (const float*)d_in[5];
    float* out = (float*)d_out;

    // workspace layout (~20.2 MB)
    unsigned int* h_bf = (unsigned int*)d_ws;                   // 12.8 MB
    float* asrc = (float*)(h_bf + (size_t)N_NODES * 64);        // 1.6 MB
    float* adst = asrc + (size_t)N_NODES * HEADS;               // 1.6 MB
    unsigned int* bin = (unsigned int*)(adst + (size_t)N_NODES * HEADS); // 4.1 MB
    int* cnt = (int*)(bin + (size_t)NBUCK * BCAP);              // 782 ints

    hipMemsetAsync(cnt, 0, NBUCK * sizeof(int), stream);
    k_gemm<<<(N_NODES + 63) / 64, 512, 0, stream>>>(x, W, att_s, att_d,
                                                    h_bf, asrc, adst);
    k_bin<<<BINB, 512, 0, stream>>>(ei, cnt, bin);
    k_aggr<<<NBUCK, 512, 0, stream>>>(h_bf, bin, cnt, asrc, adst, bias, out);
}

// Round 10
// 179.070 us; speedup vs baseline: 1.1528x; 1.1528x over previous
//
#include <hip/hip_runtime.h>

#define N_NODES 50000
#define N_EDGES 800000
#define HEADS 8
#define NEG_SLOPE 0.2f
#define EPS 1e-16f
#define NBUCK 782            // ceil(50000/64) buckets of 64 dst nodes
#define BNODES 64
#define BCAP 1312            // bucket capacity (load ~Poisson(1023); +9 sigma)
#define GEMMB 782            // gemm blocks (64 rows each)
#define BINB 250             // bin blocks (placed FIRST in the grid)
#define EPB 3200             // 800000 / 250 edges per bin block
#define LOG2E 1.4426950408889634f

// bf16x2 pack/unpack (RNE), exact unpack
__device__ inline unsigned int f2_to_bf2(float a, float b) {
    unsigned int ua = __float_as_uint(a);
    unsigned int ub = __float_as_uint(b);
    ua += 0x7fff + ((ua >> 16) & 1);
    ub += 0x7fff + ((ub >> 16) & 1);
    return (ua >> 16) | (ub & 0xffff0000u);
}
__device__ inline float2 bf2_to_f2(unsigned int u) {
    return make_float2(__uint_as_float(u << 16),
                       __uint_as_float(u & 0xffff0000u));
}

// LDS union: gemm path uses xs (32 KB); bin path uses b (25.3 KB).
union SMem {
    float xs[128 * 64];                   // 32 KB, [k][node]
    struct {
        unsigned int srt[EPB];            // 12.8 KB
        int hist[NBUCK];
        int base[NBUCK];
        int cur[NBUCK];
        int gbase[NBUCK];                 // 12.5 KB
        int wsum[8];
    } b;
};

// ---------------------------------------------------------------------------
// Fused kernel (r7 version, proven 54.9 us). Blocks [0, BINB) bin edges;
// blocks [BINB, BINB+GEMMB) run the x@W GEMM with the sched_barrier-pinned
// ping-pong pipeline. r9's zero-LDS variant regressed (W L1-capacity-missed
// every k-group); reverted.
// ---------------------------------------------------------------------------
__global__ __launch_bounds__(512, 4) void k_fused(const float* __restrict__ x,
                                                  const float* __restrict__ W,
                                                  const float* __restrict__ att_s,
                                                  const float* __restrict__ att_d,
                                                  const int* __restrict__ ei,
                                                  unsigned int* __restrict__ h_bf,
                                                  float* __restrict__ asrc,
                                                  float* __restrict__ adst,
                                                  int* __restrict__ cnt,
                                                  unsigned int* __restrict__ bin) {
    __shared__ SMem sm;
    const int tid = threadIdx.x;

    if (blockIdx.x >= BINB) {
        // ------------------------- GEMM path -------------------------
        const int row0 = (blockIdx.x - BINB) * 64;

        for (int i = tid; i < 64 * 32; i += 512) {
            const int r = i & 63;
            const int k4 = i >> 6;
            const int row = row0 + r;
            float4 v = make_float4(0.f, 0.f, 0.f, 0.f);
            if (row < N_NODES) v = ((const float4*)x)[row * 32 + k4];
            float* d = sm.xs + (k4 * 4) * 64 + r;   // lane-consecutive writes
            d[0]   = v.x;
            d[64]  = v.y;
            d[128] = v.z;
            d[192] = v.w;
        }
        __syncthreads();

        const int colg = tid & 31;
        const int rowg = tid >> 5;                  // 0..15, 4 rows each
        float acc[4][4];
#pragma unroll
        for (int r = 0; r < 4; ++r)
#pragma unroll
            for (int j = 0; j < 4; ++j) acc[r][j] = 0.f;

        const float4* Wb = ((const float4*)W) + colg;   // stride 32 per k
        const float*  Xb = sm.xs + rowg * 4;            // stride 64 per k

        float4 wA[4], xA[4];
#pragma unroll
        for (int i = 0; i < 4; ++i) {
            wA[i] = Wb[i * 32];
            xA[i] = *(const float4*)(Xb + i * 64);
        }

        for (int k0 = 0; k0 < 128; k0 += 8) {
            // issue group B loads (k0+4 .. k0+7)
            float4 wB[4], xB[4];
#pragma unroll
            for (int i = 0; i < 4; ++i) {
                wB[i] = Wb[(k0 + 4 + i) * 32];
                xB[i] = *(const float4*)(Xb + (k0 + 4 + i) * 64);
            }
            __builtin_amdgcn_sched_barrier(0);
            // FMAs on group A (k0 .. k0+3)
#pragma unroll
            for (int i = 0; i < 4; ++i) {
                const float xv[4] = {xA[i].x, xA[i].y, xA[i].z, xA[i].w};
                const float wv[4] = {wA[i].x, wA[i].y, wA[i].z, wA[i].w};
#pragma unroll
                for (int r = 0; r < 4; ++r)
#pragma unroll
                    for (int j = 0; j < 4; ++j) acc[r][j] += xv[r] * wv[j];
            }
            // issue group A loads for next iteration (wraps dead on last)
            const int kn = (k0 + 8) & 127;
#pragma unroll
            for (int i = 0; i < 4; ++i) {
                wA[i] = Wb[(kn + i) * 32];
                xA[i] = *(const float4*)(Xb + (kn + i) * 64);
            }
            __builtin_amdgcn_sched_barrier(0);
            // FMAs on group B (k0+4 .. k0+7)
#pragma unroll
            for (int i = 0; i < 4; ++i) {
                const float xv[4] = {xB[i].x, xB[i].y, xB[i].z, xB[i].w};
                const float wv[4] = {wB[i].x, wB[i].y, wB[i].z, wB[i].w};
#pragma unroll
                for (int r = 0; r < 4; ++r)
#pragma unroll
                    for (int j = 0; j < 4; ++j) acc[r][j] += xv[r] * wv[j];
            }
        }

        const int hd = colg >> 2;
        const float4 asv = ((const float4*)att_s)[colg];
        const float4 adv = ((const float4*)att_d)[colg];
#pragma unroll
        for (int r = 0; r < 4; ++r) {
            const int row = row0 + rowg * 4 + r;
            float ps = acc[r][0] * asv.x + acc[r][1] * asv.y +
                       acc[r][2] * asv.z + acc[r][3] * asv.w;
            float pd = acc[r][0] * adv.x + acc[r][1] * adv.y +
                       acc[r][2] * adv.z + acc[r][3] * adv.w;
            ps += __shfl_xor(ps, 1); ps += __shfl_xor(ps, 2);
            pd += __shfl_xor(pd, 1); pd += __shfl_xor(pd, 2);
            if (row < N_NODES) {
                if ((colg & 3) == 0) {
                    asrc[row * 8 + hd] = ps * LOG2E;   // pre-scale for exp2
                    adst[row * 8 + hd] = pd * LOG2E;
                }
                uint2 p;
                p.x = f2_to_bf2(acc[r][0], acc[r][1]);
                p.y = f2_to_bf2(acc[r][2], acc[r][3]);
                ((uint2*)h_bf)[row * 32 + colg] = p;
            }
        }
    } else {
        // ------------------------- BIN path -------------------------
        const int e0 = blockIdx.x * EPB;
        const int lane = tid & 63;
        const int wid = tid >> 6;                   // 0..7

        for (int b = tid; b < NBUCK; b += 512) sm.b.hist[b] = 0;
        __syncthreads();

        // pass 1: histogram (bucket = dst >> 6)
        for (int i = tid; i < EPB; i += 512)
            atomicAdd(&sm.b.hist[ei[N_EDGES + e0 + i] >> 6], 1);
        __syncthreads();

        // exclusive scan: thread owns buckets 2t..2t+1 (2*512 >= NBUCK),
        // two-level shfl scan of per-thread totals
        const int b2 = tid * 2;
        const int l0 = (b2     < NBUCK) ? sm.b.hist[b2]     : 0;
        const int l1 = (b2 + 1 < NBUCK) ? sm.b.hist[b2 + 1] : 0;
        const int tot = l0 + l1;
        int inc = tot;
#pragma unroll
        for (int off = 1; off < 64; off <<= 1) {
            const int u = __shfl_up(inc, off);
            if (lane >= off) inc += u;
        }
        if (lane == 63) sm.b.wsum[wid] = inc;
        __syncthreads();
        int run = inc - tot;
        for (int w2 = 0; w2 < wid; ++w2) run += sm.b.wsum[w2];
        if (b2     < NBUCK) { sm.b.base[b2]     = run; sm.b.cur[b2]     = run; } run += l0;
        if (b2 + 1 < NBUCK) { sm.b.base[b2 + 1] = run; sm.b.cur[b2 + 1] = run; }
        __syncthreads();

        // pass 2: scatter into sorted LDS
        for (int i = tid; i < EPB; i += 512) {
            const unsigned src = (unsigned)ei[e0 + i];
            const unsigned dst = (unsigned)ei[N_EDGES + e0 + i];
            const int p = atomicAdd(&sm.b.cur[dst >> 6], 1);
            if ((unsigned)p < (unsigned)EPB) sm.b.srt[p] = (dst << 16) | src;
        }
        __syncthreads();

        // reserve global ranges (one atomic per non-empty bucket)
        for (int b = tid; b < NBUCK; b += 512)
            sm.b.gbase[b] = (sm.b.hist[b] > 0) ? atomicAdd(&cnt[b], sm.b.hist[b]) : 0;
        __syncthreads();

        // contiguous run copy-out
        for (int p = tid; p < EPB; p += 512) {
            const unsigned rec = sm.b.srt[p];
            const int b = rec >> 22;
            if (b < NBUCK) {
                const int pos = sm.b.gbase[b] + (p - sm.b.base[b]);
                if ((unsigned)pos < (unsigned)BCAP)
                    bin[(size_t)b * BCAP + pos] = rec;
            }
        }
    }
}

// ---------------------------------------------------------------------------
// Aggregation. r9 discovery: VGPR_Count=32 means the declared s[16]/hv[16]
// batch arrays were NOT register-resident as a batch — the compiler
// collapsed the issue-early gathers into load->use chains (MLP~1), making
// the kernel a pointer-chase: ~830 gathers/SIMD x ~900cy / ~6 waves = 52us
// = the whole measured time. Fix: sched_barrier(0) fences pin the 3-phase
// schedule {srt reads | 16 gathers issued | compute}, forcing 16 loads in
// flight (VGPR must rise to ~80+; that is the observable).
// ---------------------------------------------------------------------------
__global__ __launch_bounds__(512) void k_aggr(const unsigned int* __restrict__ h_bf,
                                              const unsigned int* __restrict__ bin,
                                              const int* __restrict__ cnt,
                                              const float* __restrict__ asrc,
                                              const float* __restrict__ adst,
                                              const float* __restrict__ bias,
                                              float* __restrict__ out) {
    __shared__ unsigned int srt[BCAP];    // 5.2 KB
    __shared__ int hist[BNODES], base[BNODES], scn[BNODES];

    const int bkt = blockIdx.x;
    const int tid = threadIdx.x;
    const int wid = tid >> 6;
    const int lane = tid & 63;
    const int hd = lane >> 3;     // consumer head (channels lane*2, lane*2+1)
    const int eslot = lane >> 3;  // producer edge slot 0..7
    const int phead = lane & 7;   // producer head

    const int cntb = min(cnt[bkt], BCAP);
    const unsigned int* seg = bin + (size_t)bkt * BCAP;

    if (tid < BNODES) hist[tid] = 0;
    __syncthreads();

    // single pass: read seg once, rank via LDS atomic, keep in registers
    unsigned int myrec[3];
    int myrank[3];
    int nrec = 0;
    for (int i = tid; i < cntb; i += 512) {
        const unsigned rec = seg[i];
        myrank[nrec] = atomicAdd(&hist[(rec >> 16) & 63], 1);
        myrec[nrec] = rec;
        ++nrec;
    }
    __syncthreads();

    if (tid < BNODES) scn[tid] = hist[tid];
    __syncthreads();
    for (int off = 1; off < BNODES; off <<= 1) {
        int v = 0;
        if (tid < BNODES && tid >= off) v = scn[tid - off];
        __syncthreads();
        if (tid < BNODES) scn[tid] += v;
        __syncthreads();
    }
    if (tid < BNODES) base[tid] = scn[tid] - hist[tid];
    __syncthreads();

    for (int k = 0; k < nrec; ++k) {
        const unsigned rec = myrec[k];
        const int p = base[(rec >> 16) & 63] + myrank[k];
        if ((unsigned)p < (unsigned)BCAP) srt[p] = rec;
    }
    __syncthreads();

    // per-wave node processing: wave wid handles dlocal = wid, wid+8, ...
    for (int dl = wid; dl < BNODES; dl += 8) {
        const int d = bkt * BNODES + dl;
        if (d >= N_NODES) continue;
        const int jb = base[dl];
        const int jn = hist[dl];

        const float adst_h = adst[d * 8 + hd];      // consumer head
        const float adst_p = adst[d * 8 + phead];   // producer head
        const float asrc_self = asrc[d * 8 + hd];
        const float2 hdv = bf2_to_f2(h_bf[d * 64 + lane]);

        float es = asrc_self + adst_h;
        es = fmaxf(es, NEG_SLOPE * es);       // LeakyReLU, slope<1
        const float exs = exp2f(es);          // logits pre-scaled by log2e

        float2 acc = make_float2(0.f, 0.f);
        float den = 0.f;

        for (int j0 = 0; j0 < jn; j0 += 16) {
            // phase 1: srt reads (LDS) — 16 broadcast ids + 2 producer ids
            int s[16];
#pragma unroll
            for (int i = 0; i < 16; ++i) {
                const int jj = j0 + i;
                s[i] = (int)(srt[jb + ((jj < jn) ? jj : jn - 1)] & 0xffffu);
            }
            const int ia = j0 + eslot;
            const int ib = ia + 8;
            const int sa = (int)(srt[jb + min(ia, jn - 1)] & 0xffffu);
            const int sb = (int)(srt[jb + min(ib, jn - 1)] & 0xffffu);
            __builtin_amdgcn_sched_barrier(0);

            // phase 2: issue ALL gathers, consume nothing (16-deep MLP)
            unsigned int hv[16];
#pragma unroll
            for (int i = 0; i < 16; ++i) hv[i] = h_bf[s[i] * 64 + lane];
            const float aA = asrc[sa * 8 + phead];
            const float aB = asrc[sb * 8 + phead];
            __builtin_amdgcn_sched_barrier(0);

            // phase 3: compute
            float eA = aA + adst_p;
            float eB = aB + adst_p;
            eA = fmaxf(eA, NEG_SLOPE * eA);
            eB = fmaxf(eB, NEG_SLOPE * eB);
            const float exA = (ia < jn) ? exp2f(eA) : 0.f;
            const float exB = (ib < jn) ? exp2f(eB) : 0.f;

#pragma unroll
            for (int i = 0; i < 16; ++i) {
                // producer of (edge i, head hd) is lane ((i&7)<<3) | hd
                const float ex = __shfl((i < 8) ? exA : exB,
                                        ((i & 7) << 3) | hd, 64);
                const float2 hv2 = bf2_to_f2(hv[i]);
                acc.x += ex * hv2.x;
                acc.y += ex * hv2.y;
                den += ex;
            }
        }

        const float dtot = den + exs + EPS;
        const float2 b2 = ((const float2*)bias)[lane];
        float vx = (acc.x + exs * hdv.x) / dtot + b2.x;
        float vy = (acc.y + exs * hdv.y) / dtot + b2.y;
        vx = (vx > 0.f) ? vx : expm1f(vx);
        vy = (vy > 0.f) ? vy : expm1f(vy);
        ((float2*)out)[d * 64 + lane] = make_float2(vx, vy);
    }
}

extern "C" void kernel_launch(void* const* d_in, const int* in_sizes, int n_in,
                              void* d_out, int out_size, void* d_ws, size_t ws_size,
                              hipStream_t stream) {
    const float* x     = (const float*)d_in[0];
    const int*   ei    = (const int*)d_in[1];
    const float* W     = (const float*)d_in[2];
    const float* att_s = (const float*)d_in[3];
    const float* att_d = (const float*)d_in[4];
    const float* bias  = (const float*)d_in[5];
    float* out = (float*)d_out;

    // workspace layout (~20.2 MB)
    unsigned int* h_bf = (unsigned int*)d_ws;                   // 12.8 MB
    float* asrc = (float*)(h_bf + (size_t)N_NODES * 64);        // 1.6 MB
    float* adst = asrc + (size_t)N_NODES * HEADS;               // 1.6 MB
    unsigned int* bin = (unsigned int*)(adst + (size_t)N_NODES * HEADS); // 4.1 MB
    int* cnt = (int*)(bin + (size_t)NBUCK * BCAP);              // 782 ints

    hipMemsetAsync(cnt, 0, NBUCK * sizeof(int), stream);
    k_fused<<<BINB + GEMMB, 512, 0, stream>>>(x, W, att_s, att_d, ei,
                                              h_bf, asrc, adst, cnt, bin);
    k_aggr<<<NBUCK, 512, 0, stream>>>(h_bf, bin, cnt, asrc, adst, bias, out);
}

// Round 11
// 176.124 us; speedup vs baseline: 1.1720x; 1.0167x over previous
//
#include <hip/hip_runtime.h>

#define N_NODES 50000
#define N_EDGES 800000
#define HEADS 8
#define NEG_SLOPE 0.2f
#define EPS 1e-16f
#define NBUCK 782            // ceil(50000/64) buckets of 64 dst nodes
#define BNODES 64
#define BCAP 1280            // bucket capacity (load ~Poisson(1024); +8 sigma)
#define BINB 250             // bin blocks
#define EPB 3200             // 800000 / 250 edges per bin block
#define LOG2E 1.4426950408889634f

typedef __bf16 bf16x8 __attribute__((ext_vector_type(8)));
typedef float f32x4 __attribute__((ext_vector_type(4)));

// bf16x2 pack/unpack (RNE), exact unpack
__device__ inline unsigned int f2_to_bf2(float a, float b) {
    unsigned int ua = __float_as_uint(a);
    unsigned int ub = __float_as_uint(b);
    ua += 0x7fff + ((ua >> 16) & 1);
    ub += 0x7fff + ((ub >> 16) & 1);
    return (ua >> 16) | (ub & 0xffff0000u);
}
__device__ inline float2 bf2_to_f2(unsigned int u) {
    return make_float2(__uint_as_float(u << 16),
                       __uint_as_float(u & 0xffff0000u));
}

// ---------------------------------------------------------------------------
// Kernel 0: one-shot W swizzle into MFMA fragment order, split precision.
// Fragment (kstep, n, lane, e): k = kstep*32 + (lane>>4)*8 + e,
// col = n*16 + (lane&15). hi = bf16(v), lo = bf16(v - hi).
// 2048 threads, one (kstep,n,lane) triple each; 16B coalesced stores.
// ---------------------------------------------------------------------------
__global__ __launch_bounds__(512) void k_prepW(const float* __restrict__ W,
                                               unsigned int* __restrict__ wfrag) {
    const int t = blockIdx.x * 512 + threadIdx.x;
    if (t >= 2048) return;
    const int lane = t & 63;
    const int n = (t >> 6) & 7;
    const int kstep = t >> 9;
    const int c = n * 16 + (lane & 15);
    const int kb = kstep * 32 + (lane >> 4) * 8;

    unsigned int hi[8], lo[8];
#pragma unroll
    for (int e = 0; e < 8; ++e) {
        const float v = W[(kb + e) * 128 + c];
        const __bf16 h = (__bf16)v;
        const __bf16 l = (__bf16)(v - (float)h);
        hi[e] = (unsigned int)__builtin_bit_cast(unsigned short, h);
        lo[e] = (unsigned int)__builtin_bit_cast(unsigned short, l);
    }
    uint4 ph, pl;
    ph.x = hi[0] | (hi[1] << 16); ph.y = hi[2] | (hi[3] << 16);
    ph.z = hi[4] | (hi[5] << 16); ph.w = hi[6] | (hi[7] << 16);
    pl.x = lo[0] | (lo[1] << 16); pl.y = lo[2] | (lo[3] << 16);
    pl.z = lo[4] | (lo[5] << 16); pl.w = lo[6] | (lo[7] << 16);
    uint4* dst = (uint4*)wfrag;
    dst[t] = ph;             // hi fragments: [0, 2048)
    dst[2048 + t] = pl;      // lo fragments: [2048, 4096)
}

// ---------------------------------------------------------------------------
// Kernel 1: MFMA GEMM h = x@W. 6 rounds of scheduling levers left the fp32
// VALU path at ~55us (floor 10.4us); MfmaUtil was 0.0 all along. This uses
// v_mfma_f32_16x16x32_bf16 with split-precision inputs (hi/lo bf16,
// 3 MFMAs: hi*hi + hi*lo + lo*hi -> rel err ~2^-17, far below the bf16
// output quantization that dominates absmax). Layout safety: A and B use
// the SAME (lane>>4,e)->k formula, so the result is invariant under the
// HW's internal k-permutation; only m=lane&15 / n=lane&15 / the
// m89-verified D layout (col=lane&15, row=(lane>>4)*4+reg) matter.
// Wave computes a 16x128 strip; block = 4 waves = 64 rows; no LDS.
// ---------------------------------------------------------------------------
__global__ __launch_bounds__(256) void k_gemm(const float* __restrict__ x,
                                              const unsigned int* __restrict__ wfrag,
                                              const float* __restrict__ att_s,
                                              const float* __restrict__ att_d,
                                              unsigned int* __restrict__ h_bf,
                                              float* __restrict__ asrc,
                                              float* __restrict__ adst) {
    const int tid = threadIdx.x;
    const int w = tid >> 6;
    const int l = tid & 63;
    const int m = l & 15;            // A-row / B-col within tile
    const int g = l >> 4;            // k-group
    const int row0 = blockIdx.x * 64 + w * 16;
    const int rowa = row0 + m;
    const int rowc = (rowa < N_NODES) ? rowa : (N_NODES - 1);
    const float* xrow = x + (size_t)rowc * 128 + g * 8;

    f32x4 acc[8];
#pragma unroll
    for (int n = 0; n < 8; ++n) acc[n] = (f32x4){0.f, 0.f, 0.f, 0.f};

    const bf16x8* Whi = (const bf16x8*)wfrag;
    const bf16x8* Wlo = Whi + 2048;

#pragma unroll
    for (int ks = 0; ks < 4; ++ks) {
        const float4 xa = *(const float4*)(xrow + ks * 32);
        const float4 xb = *(const float4*)(xrow + ks * 32 + 4);
        const float xv[8] = {xa.x, xa.y, xa.z, xa.w, xb.x, xb.y, xb.z, xb.w};
        bf16x8 ahi, alo;
#pragma unroll
        for (int e = 0; e < 8; ++e) {
            const __bf16 h = (__bf16)xv[e];
            ahi[e] = h;
            alo[e] = (__bf16)(xv[e] - (float)h);
        }
#pragma unroll
        for (int n = 0; n < 8; ++n) {
            const bf16x8 bh = Whi[(ks * 8 + n) * 64 + l];
            const bf16x8 bl = Wlo[(ks * 8 + n) * 64 + l];
            acc[n] = __builtin_amdgcn_mfma_f32_16x16x32_bf16(ahi, bh, acc[n], 0, 0, 0);
            acc[n] = __builtin_amdgcn_mfma_f32_16x16x32_bf16(alo, bh, acc[n], 0, 0, 0);
            acc[n] = __builtin_amdgcn_mfma_f32_16x16x32_bf16(ahi, bl, acc[n], 0, 0, 0);
        }
    }

    // Epilogue. Lane l holds D[g*4+r][n*16+m] (m89-verified layout).
    // Tile n == head n; channel within head == m.
#pragma unroll
    for (int n = 0; n < 8; ++n) {
        const float asv = att_s[n * 16 + m];
        const float adv = att_d[n * 16 + m];
#pragma unroll
        for (int r = 0; r < 4; ++r) {
            const int rowr = row0 + g * 4 + r;
            const float hv = acc[n][r];
            float ps = hv * asv;
            float pd = hv * adv;
            ps += __shfl_xor(ps, 1); ps += __shfl_xor(ps, 2);
            ps += __shfl_xor(ps, 4); ps += __shfl_xor(ps, 8);
            pd += __shfl_xor(pd, 1); pd += __shfl_xor(pd, 2);
            pd += __shfl_xor(pd, 4); pd += __shfl_xor(pd, 8);
            const float hp = __shfl_xor(hv, 1);   // odd-channel partner
            if (rowr < N_NODES) {
                if (m == 0) {
                    asrc[rowr * 8 + n] = ps * LOG2E;   // pre-scale for exp2
                    adst[rowr * 8 + n] = pd * LOG2E;
                }
                if (!(m & 1))
                    h_bf[(size_t)rowr * 64 + n * 8 + (m >> 1)] = f2_to_bf2(hv, hp);
            }
        }
    }
}

// ---------------------------------------------------------------------------
// Kernel 2: edge bucket-binning. 250 blocks x 512 threads x 3200 edges.
// LDS counting sort by 64-node bucket, two-level shfl scan, one global
// atomic per (block,bucket), contiguous run copy-out. Record=(dst<<16)|src.
// ---------------------------------------------------------------------------
__global__ __launch_bounds__(512) void k_bin(const int* __restrict__ ei,
                                             int* __restrict__ cnt,
                                             unsigned int* __restrict__ bin) {
    __shared__ unsigned int srt[EPB];     // 12.8 KB
    __shared__ int hist[NBUCK];
    __shared__ int base[NBUCK];
    __shared__ int cur[NBUCK];
    __shared__ int gbase[NBUCK];
    __shared__ int wsum[8];
    const int tid = threadIdx.x;
    const int lane = tid & 63;
    const int wid = tid >> 6;
    const int e0 = blockIdx.x * EPB;

    for (int b = tid; b < NBUCK; b += 512) hist[b] = 0;
    __syncthreads();

    for (int i = tid; i < EPB; i += 512)
        atomicAdd(&hist[ei[N_EDGES + e0 + i] >> 6], 1);
    __syncthreads();

    const int b2 = tid * 2;
    const int l0 = (b2     < NBUCK) ? hist[b2]     : 0;
    const int l1 = (b2 + 1 < NBUCK) ? hist[b2 + 1] : 0;
    const int tot = l0 + l1;
    int inc = tot;
#pragma unroll
    for (int off = 1; off < 64; off <<= 1) {
        const int u = __shfl_up(inc, off);
        if (lane >= off) inc += u;
    }
    if (lane == 63) wsum[wid] = inc;
    __syncthreads();
    int run = inc - tot;
    for (int w2 = 0; w2 < wid; ++w2) run += wsum[w2];
    if (b2     < NBUCK) { base[b2]     = run; cur[b2]     = run; } run += l0;
    if (b2 + 1 < NBUCK) { base[b2 + 1] = run; cur[b2 + 1] = run; }
    __syncthreads();

    for (int i = tid; i < EPB; i += 512) {
        const unsigned src = (unsigned)ei[e0 + i];
        const unsigned dst = (unsigned)ei[N_EDGES + e0 + i];
        const int p = atomicAdd(&cur[dst >> 6], 1);
        if ((unsigned)p < (unsigned)EPB) srt[p] = (dst << 16) | src;
    }
    __syncthreads();

    for (int b = tid; b < NBUCK; b += 512)
        gbase[b] = (hist[b] > 0) ? atomicAdd(&cnt[b], hist[b]) : 0;
    __syncthreads();

    for (int p = tid; p < EPB; p += 512) {
        const unsigned rec = srt[p];
        const int b = rec >> 22;
        if (b < NBUCK) {
            const int pos = gbase[b] + (p - base[b]);
            if ((unsigned)pos < (unsigned)BCAP)
                bin[(size_t)b * BCAP + pos] = rec;
        }
    }
}

// ---------------------------------------------------------------------------
// Kernel 3: aggregation (r5 proven version, ~53.4us; r10's fenced variant
// regressed to 56 and its VGPR observable refuted the MLP=1 theory — the
// kernel is near its issue+gather-traffic bound). One block (8 waves) per
// bucket; counting sort; clamped depth-16 batches; producer/consumer ex.
// ---------------------------------------------------------------------------
__global__ __launch_bounds__(512) void k_aggr(const unsigned int* __restrict__ h_bf,
                                              const unsigned int* __restrict__ bin,
                                              const int* __restrict__ cnt,
                                              const float* __restrict__ asrc,
                                              const float* __restrict__ adst,
                                              const float* __restrict__ bias,
                                              float* __restrict__ out) {
    __shared__ unsigned int srt[BCAP];    // 5.0 KB
    __shared__ int hist[BNODES], base[BNODES], scn[BNODES];

    const int bkt = blockIdx.x;
    const int tid = threadIdx.x;
    const int wid = tid >> 6;
    const int lane = tid & 63;
    const int hd = lane >> 3;     // consumer head (channels lane*2, lane*2+1)
    const int eslot = lane >> 3;  // producer edge slot 0..7
    const int phead = lane & 7;   // producer head

    const int cntb = min(cnt[bkt], BCAP);
    const unsigned int* seg = bin + (size_t)bkt * BCAP;

    if (tid < BNODES) hist[tid] = 0;
    __syncthreads();

    unsigned int myrec[3];
    int myrank[3];
    int nrec = 0;
    for (int i = tid; i < cntb; i += 512) {
        const unsigned rec = seg[i];
        myrank[nrec] = atomicAdd(&hist[(rec >> 16) & 63], 1);
        myrec[nrec] = rec;
        ++nrec;
    }
    __syncthreads();

    if (tid < BNODES) scn[tid] = hist[tid];
    __syncthreads();
    for (int off = 1; off < BNODES; off <<= 1) {
        int v = 0;
        if (tid < BNODES && tid >= off) v = scn[tid - off];
        __syncthreads();
        if (tid < BNODES) scn[tid] += v;
        __syncthreads();
    }
    if (tid < BNODES) base[tid] = scn[tid] - hist[tid];
    __syncthreads();

    for (int k = 0; k < nrec; ++k) {
        const unsigned rec = myrec[k];
        const int p = base[(rec >> 16) & 63] + myrank[k];
        if ((unsigned)p < (unsigned)BCAP) srt[p] = rec;
    }
    __syncthreads();

    for (int dl = wid; dl < BNODES; dl += 8) {
        const int d = bkt * BNODES + dl;
        if (d >= N_NODES) continue;
        const int jb = base[dl];
        const int jn = hist[dl];

        const float adst_h = adst[d * 8 + hd];      // consumer head
        const float adst_p = adst[d * 8 + phead];   // producer head
        const float asrc_self = asrc[d * 8 + hd];
        const float2 hdv = bf2_to_f2(h_bf[d * 64 + lane]);

        float es = asrc_self + adst_h;
        es = fmaxf(es, NEG_SLOPE * es);       // LeakyReLU, slope<1
        const float exs = exp2f(es);          // logits pre-scaled by log2e

        float2 acc = make_float2(0.f, 0.f);
        float den = 0.f;

        for (int j0 = 0; j0 < jn; j0 += 16) {
            int s[16];
#pragma unroll
            for (int i = 0; i < 16; ++i) {
                const int jj = j0 + i;
                s[i] = (int)(srt[jb + ((jj < jn) ? jj : jn - 1)] & 0xffffu);
            }
            unsigned int hv[16];
#pragma unroll
            for (int i = 0; i < 16; ++i) hv[i] = h_bf[s[i] * 64 + lane];

            const int ia = j0 + eslot;
            const int ib = ia + 8;
            const int sa = (int)(srt[jb + min(ia, jn - 1)] & 0xffffu);
            const int sb = (int)(srt[jb + min(ib, jn - 1)] & 0xffffu);
            float eA = asrc[sa * 8 + phead] + adst_p;
            float eB = asrc[sb * 8 + phead] + adst_p;
            eA = fmaxf(eA, NEG_SLOPE * eA);
            eB = fmaxf(eB, NEG_SLOPE * eB);
            const float exA = (ia < jn) ? exp2f(eA) : 0.f;
            const float exB = (ib < jn) ? exp2f(eB) : 0.f;

#pragma unroll
            for (int i = 0; i < 16; ++i) {
                const float ex = __shfl((i < 8) ? exA : exB,
                                        ((i & 7) << 3) | hd, 64);
                const float2 hv2 = bf2_to_f2(hv[i]);
                acc.x += ex * hv2.x;
                acc.y += ex * hv2.y;
                den += ex;
            }
        }

        const float dtot = den + exs + EPS;
        const float2 b2 = ((const float2*)bias)[lane];
        float vx = (acc.x + exs * hdv.x) / dtot + b2.x;
        float vy = (acc.y + exs * hdv.y) / dtot + b2.y;
        vx = (vx > 0.f) ? vx : expm1f(vx);
        vy = (vy > 0.f) ? vy : expm1f(vy);
        ((float2*)out)[d * 64 + lane] = make_float2(vx, vy);
    }
}

extern "C" void kernel_launch(void* const* d_in, const int* in_sizes, int n_in,
                              void* d_out, int out_size, void* d_ws, size_t ws_size,
                              hipStream_t stream) {
    const float* x     = (const float*)d_in[0];
    const int*   ei    = (const int*)d_in[1];
    const float* W     = (const float*)d_in[2];
    const float* att_s = (const float*)d_in[3];
    const float* att_d = (const float*)d_in[4];
    const float* bias  = (const float*)d_in[5];
    float* out = (float*)d_out;

    // workspace layout (~20.07 MB, within the footprint used all session)
    unsigned int* h_bf = (unsigned int*)d_ws;                   // 12.8 MB
    float* asrc = (float*)(h_bf + (size_t)N_NODES * 64);        // 1.6 MB
    float* adst = asrc + (size_t)N_NODES * HEADS;               // 1.6 MB
    unsigned int* bin = (unsigned int*)(adst + (size_t)N_NODES * HEADS); // 4.0 MB
    unsigned int* wfrag = bin + (size_t)NBUCK * BCAP;           // 64 KB (16B-aligned)
    int* cnt = (int*)(wfrag + 16384);                           // 782 ints

    hipMemsetAsync(cnt, 0, NBUCK * sizeof(int), stream);
    k_prepW<<<4, 512, 0, stream>>>(W, wfrag);
    k_gemm<<<(N_NODES + 63) / 64, 256, 0, stream>>>(x, wfrag, att_s, att_d,
                                                    h_bf, asrc, adst);
    k_bin<<<BINB, 512, 0, stream>>>(ei, cnt, bin);
    k_aggr<<<NBUCK, 512, 0, stream>>>(h_bf, bin, cnt, asrc, adst, bias, out);
}

// Round 13
// 171.366 us; speedup vs baseline: 1.2046x; 1.0278x over previous
//
#include <hip/hip_runtime.h>

#define N_NODES 50000
#define N_EDGES 800000
#define HEADS 8
#define NEG_SLOPE 0.2f
#define EPS 1e-16f
#define NBUCK 782            // ceil(50000/64) buckets of 64 dst nodes
#define BNODES 64
#define BCAP 1280            // bucket capacity (load ~Poisson(1024); +8 sigma)
#define BINB 250             // bin blocks
#define EPB 3200             // 800000 / 250 edges per bin block
#define LOG2E 1.4426950408889634f

typedef __bf16 bf16x8 __attribute__((ext_vector_type(8)));
typedef float f32x4 __attribute__((ext_vector_type(4)));

// bf16x2 pack/unpack (RNE), exact unpack
__device__ inline unsigned int f2_to_bf2(float a, float b) {
    unsigned int ua = __float_as_uint(a);
    unsigned int ub = __float_as_uint(b);
    ua += 0x7fff + ((ua >> 16) & 1);
    ub += 0x7fff + ((ub >> 16) & 1);
    return (ua >> 16) | (ub & 0xffff0000u);
}
__device__ inline float2 bf2_to_f2(unsigned int u) {
    return make_float2(__uint_as_float(u << 16),
                       __uint_as_float(u & 0xffff0000u));
}

// ---------------------------------------------------------------------------
// Kernel 0: one-shot W swizzle into MFMA fragment order, split precision.
// Fragment (kstep, n, lane, e): k = kstep*32 + (lane>>4)*8 + e,
// col = n*16 + (lane&15). hi = bf16(v), lo = bf16(v - hi).
// ---------------------------------------------------------------------------
__global__ __launch_bounds__(512) void k_prepW(const float* __restrict__ W,
                                               unsigned int* __restrict__ wfrag) {
    const int t = blockIdx.x * 512 + threadIdx.x;
    if (t >= 2048) return;
    const int lane = t & 63;
    const int n = (t >> 6) & 7;
    const int kstep = t >> 9;
    const int c = n * 16 + (lane & 15);
    const int kb = kstep * 32 + (lane >> 4) * 8;

    unsigned int hi[8], lo[8];
#pragma unroll
    for (int e = 0; e < 8; ++e) {
        const float v = W[(kb + e) * 128 + c];
        const __bf16 h = (__bf16)v;
        const __bf16 l = (__bf16)(v - (float)h);
        hi[e] = (unsigned int)__builtin_bit_cast(unsigned short, h);
        lo[e] = (unsigned int)__builtin_bit_cast(unsigned short, l);
    }
    uint4 ph, pl;
    ph.x = hi[0] | (hi[1] << 16); ph.y = hi[2] | (hi[3] << 16);
    ph.z = hi[4] | (hi[5] << 16); ph.w = hi[6] | (hi[7] << 16);
    pl.x = lo[0] | (lo[1] << 16); pl.y = lo[2] | (lo[3] << 16);
    pl.z = lo[4] | (lo[5] << 16); pl.w = lo[6] | (lo[7] << 16);
    uint4* dst = (uint4*)wfrag;
    dst[t] = ph;             // hi fragments: [0, 2048)
    dst[2048 + t] = pl;      // lo fragments: [2048, 4096)
}

// ---------------------------------------------------------------------------
// Kernel 1: MFMA GEMM h = x@W, B staged in LDS. r11 post-mortem: the MFMA
// version at ~50us was bound by the SAME pathology as the fp32 rounds —
// every wave re-streamed the 64KB wfrag via per-lane global loads; 64KB >
// 32KB L1, so all 72 fragment loads/strip L2-missed with latency exposed.
// Fix: stage wfrag into LDS once per block (one load phase + ONE barrier),
// inner loop = 2x ds_read_b128 + 3 MFMA — pipes the compiler schedules
// well (fine-grained lgkmcnt). 512 thr / 128 rows / 64KB LDS -> 2 blk/CU.
// Same fragments, same MFMA order as r11 -> bit-identical h (absmax must
// stay 0.03125).
// ---------------------------------------------------------------------------
__global__ __launch_bounds__(512) void k_gemm(const float* __restrict__ x,
                                              const unsigned int* __restrict__ wfrag,
                                              const float* __restrict__ att_s,
                                              const float* __restrict__ att_d,
                                              unsigned int* __restrict__ h_bf,
                                              float* __restrict__ asrc,
                                              float* __restrict__ adst) {
    __shared__ uint4 wlds[4096];          // 64 KB: hi [0,2048), lo [2048,4096)
    const int tid = threadIdx.x;

    // stage wfrag -> LDS (L2-broadcast-hot; 8 x 16B per thread)
#pragma unroll
    for (int i = 0; i < 8; ++i)
        wlds[i * 512 + tid] = ((const uint4*)wfrag)[i * 512 + tid];
    __syncthreads();

    const int w = tid >> 6;               // 0..7, wave -> 16-row strip
    const int l = tid & 63;
    const int m = l & 15;                 // A-row / B-col within tile
    const int g = l >> 4;                 // k-group
    const int row0 = blockIdx.x * 128 + w * 16;
    const int rowa = row0 + m;
    const int rowc = (rowa < N_NODES) ? rowa : (N_NODES - 1);
    const float* xrow = x + (size_t)rowc * 128 + g * 8;

    f32x4 acc[8];
#pragma unroll
    for (int n = 0; n < 8; ++n) acc[n] = (f32x4){0.f, 0.f, 0.f, 0.f};

    const bf16x8* Lhi = (const bf16x8*)wlds;
    const bf16x8* Llo = Lhi + 2048;

#pragma unroll
    for (int ks = 0; ks < 4; ++ks) {
        const float4 xa = *(const float4*)(xrow + ks * 32);
        const float4 xb = *(const float4*)(xrow + ks * 32 + 4);
        const float xv[8] = {xa.x, xa.y, xa.z, xa.w, xb.x, xb.y, xb.z, xb.w};
        bf16x8 ahi, alo;
#pragma unroll
        for (int e = 0; e < 8; ++e) {
            const __bf16 h = (__bf16)xv[e];
            ahi[e] = h;
            alo[e] = (__bf16)(xv[e] - (float)h);
        }
#pragma unroll
        for (int n = 0; n < 8; ++n) {
            const bf16x8 bh = Lhi[(ks * 8 + n) * 64 + l];
            const bf16x8 bl = Llo[(ks * 8 + n) * 64 + l];
            acc[n] = __builtin_amdgcn_mfma_f32_16x16x32_bf16(ahi, bh, acc[n], 0, 0, 0);
            acc[n] = __builtin_amdgcn_mfma_f32_16x16x32_bf16(alo, bh, acc[n], 0, 0, 0);
            acc[n] = __builtin_amdgcn_mfma_f32_16x16x32_bf16(ahi, bl, acc[n], 0, 0, 0);
        }
    }

    // Epilogue. Lane l holds D[g*4+r][n*16+m] (m89-verified layout).
#pragma unroll
    for (int n = 0; n < 8; ++n) {
        const float asv = att_s[n * 16 + m];
        const float adv = att_d[n * 16 + m];
#pragma unroll
        for (int r = 0; r < 4; ++r) {
            const int rowr = row0 + g * 4 + r;
            const float hv = acc[n][r];
            float ps = hv * asv;
            float pd = hv * adv;
            ps += __shfl_xor(ps, 1); ps += __shfl_xor(ps, 2);
            ps += __shfl_xor(ps, 4); ps += __shfl_xor(ps, 8);
            pd += __shfl_xor(pd, 1); pd += __shfl_xor(pd, 2);
            pd += __shfl_xor(pd, 4); pd += __shfl_xor(pd, 8);
            const float hp = __shfl_xor(hv, 1);   // odd-channel partner
            if (rowr < N_NODES) {
                if (m == 0) {
                    asrc[rowr * 8 + n] = ps * LOG2E;   // pre-scale for exp2
                    adst[rowr * 8 + n] = pd * LOG2E;
                }
                if (!(m & 1))
                    h_bf[(size_t)rowr * 64 + n * 8 + (m >> 1)] = f2_to_bf2(hv, hp);
            }
        }
    }
}

// ---------------------------------------------------------------------------
// Kernel 2: edge bucket-binning. 250 blocks x 512 threads x 3200 edges.
// LDS counting sort by 64-node bucket, two-level shfl scan, one global
// atomic per (block,bucket), contiguous run copy-out. Record=(dst<<16)|src.
// ---------------------------------------------------------------------------
__global__ __launch_bounds__(512) void k_bin(const int* __restrict__ ei,
                                             int* __restrict__ cnt,
                                             unsigned int* __restrict__ bin) {
    __shared__ unsigned int srt[EPB];     // 12.8 KB
    __shared__ int hist[NBUCK];
    __shared__ int base[NBUCK];
    __shared__ int cur[NBUCK];
    __shared__ int gbase[NBUCK];
    __shared__ int wsum[8];
    const int tid = threadIdx.x;
    const int lane = tid & 63;
    const int wid = tid >> 6;
    const int e0 = blockIdx.x * EPB;

    for (int b = tid; b < NBUCK; b += 512) hist[b] = 0;
    __syncthreads();

    for (int i = tid; i < EPB; i += 512)
        atomicAdd(&hist[ei[N_EDGES + e0 + i] >> 6], 1);
    __syncthreads();

    const int b2 = tid * 2;
    const int l0 = (b2     < NBUCK) ? hist[b2]     : 0;
    const int l1 = (b2 + 1 < NBUCK) ? hist[b2 + 1] : 0;
    const int tot = l0 + l1;
    int inc = tot;
#pragma unroll
    for (int off = 1; off < 64; off <<= 1) {
        const int u = __shfl_up(inc, off);
        if (lane >= off) inc += u;
    }
    if (lane == 63) wsum[wid] = inc;
    __syncthreads();
    int run = inc - tot;
    for (int w2 = 0; w2 < wid; ++w2) run += wsum[w2];
    if (b2     < NBUCK) { base[b2]     = run; cur[b2]     = run; } run += l0;
    if (b2 + 1 < NBUCK) { base[b2 + 1] = run; cur[b2 + 1] = run; }
    __syncthreads();

    for (int i = tid; i < EPB; i += 512) {
        const unsigned src = (unsigned)ei[e0 + i];
        const unsigned dst = (unsigned)ei[N_EDGES + e0 + i];
        const int p = atomicAdd(&cur[dst >> 6], 1);
        if ((unsigned)p < (unsigned)EPB) srt[p] = (dst << 16) | src;
    }
    __syncthreads();

    for (int b = tid; b < NBUCK; b += 512)
        gbase[b] = (hist[b] > 0) ? atomicAdd(&cnt[b], hist[b]) : 0;
    __syncthreads();

    for (int p = tid; p < EPB; p += 512) {
        const unsigned rec = srt[p];
        const int b = rec >> 22;
        if (b < NBUCK) {
            const int pos = gbase[b] + (p - base[b]);
            if ((unsigned)pos < (unsigned)BCAP)
                bin[(size_t)b * BCAP + pos] = rec;
        }
    }
}

// ---------------------------------------------------------------------------
// Kernel 3: aggregation (r5 proven version, ~53us; at its random-gather
// HBM ceiling ~2.56 TB/s). One block (8 waves) per bucket; counting sort;
// clamped depth-16 batches; producer/consumer ex via shfl.
// ---------------------------------------------------------------------------
__global__ __launch_bounds__(512) void k_aggr(const unsigned int* __restrict__ h_bf,
                                              const unsigned int* __restrict__ bin,
                                              const int* __restrict__ cnt,
                                              const float* __restrict__ asrc,
                                              const float* __restrict__ adst,
                                              const float* __restrict__ bias,
                                              float* __restrict__ out) {
    __shared__ unsigned int srt[BCAP];    // 5.0 KB
    __shared__ int hist[BNODES], base[BNODES], scn[BNODES];

    const int bkt = blockIdx.x;
    const int tid = threadIdx.x;
    const int wid = tid >> 6;
    const int lane = tid & 63;
    const int hd = lane >> 3;     // consumer head (channels lane*2, lane*2+1)
    const int eslot = lane >> 3;  // producer edge slot 0..7
    const int phead = lane & 7;   // producer head

    const int cntb = min(cnt[bkt], BCAP);
    const unsigned int* seg = bin + (size_t)bkt * BCAP;

    if (tid < BNODES) hist[tid] = 0;
    __syncthreads();

    unsigned int myrec[3];
    int myrank[3];
    int nrec = 0;
    for (int i = tid; i < cntb; i += 512) {
        const unsigned rec = seg[i];
        myrank[nrec] = atomicAdd(&hist[(rec >> 16) & 63], 1);
        myrec[nrec] = rec;
        ++nrec;
    }
    __syncthreads();

    if (tid < BNODES) scn[tid] = hist[tid];
    __syncthreads();
    for (int off = 1; off < BNODES; off <<= 1) {
        int v = 0;
        if (tid < BNODES && tid >= off) v = scn[tid - off];
        __syncthreads();
        if (tid < BNODES) scn[tid] += v;
        __syncthreads();
    }
    if (tid < BNODES) base[tid] = scn[tid] - hist[tid];
    __syncthreads();

    for (int k = 0; k < nrec; ++k) {
        const unsigned rec = myrec[k];
        const int p = base[(rec >> 16) & 63] + myrank[k];
        if ((unsigned)p < (unsigned)BCAP) srt[p] = rec;
    }
    __syncthreads();

    for (int dl = wid; dl < BNODES; dl += 8) {
        const int d = bkt * BNODES + dl;
        if (d >= N_NODES) continue;
        const int jb = base[dl];
        const int jn = hist[dl];

        const float adst_h = adst[d * 8 + hd];      // consumer head
        const float adst_p = adst[d * 8 + phead];   // producer head
        const float asrc_self = asrc[d * 8 + hd];
        const float2 hdv = bf2_to_f2(h_bf[d * 64 + lane]);

        float es = asrc_self + adst_h;
        es = fmaxf(es, NEG_SLOPE * es);       // LeakyReLU, slope<1
        const float exs = exp2f(es);          // logits pre-scaled by log2e

        float2 acc = make_float2(0.f, 0.f);
        float den = 0.f;

        for (int j0 = 0; j0 < jn; j0 += 16) {
            int s[16];
#pragma unroll
            for (int i = 0; i < 16; ++i) {
                const int jj = j0 + i;
                s[i] = (int)(srt[jb + ((jj < jn) ? jj : jn - 1)] & 0xffffu);
            }
            unsigned int hv[16];
#pragma unroll
            for (int i = 0; i < 16; ++i) hv[i] = h_bf[s[i] * 64 + lane];

            const int ia = j0 + eslot;
            const int ib = ia + 8;
            const int sa = (int)(srt[jb + min(ia, jn - 1)] & 0xffffu);
            const int sb = (int)(srt[jb + min(ib, jn - 1)] & 0xffffu);
            float eA = asrc[sa * 8 + phead] + adst_p;
            float eB = asrc[sb * 8 + phead] + adst_p;
            eA = fmaxf(eA, NEG_SLOPE * eA);
            eB = fmaxf(eB, NEG_SLOPE * eB);
            const float exA = (ia < jn) ? exp2f(eA) : 0.f;
            const float exB = (ib < jn) ? exp2f(eB) : 0.f;

#pragma unroll
            for (int i = 0; i < 16; ++i) {
                const float ex = __shfl((i < 8) ? exA : exB,
                                        ((i & 7) << 3) | hd, 64);
                const float2 hv2 = bf2_to_f2(hv[i]);
                acc.x += ex * hv2.x;
                acc.y += ex * hv2.y;
                den += ex;
            }
        }

        const float dtot = den + exs + EPS;
        const float2 b2 = ((const float2*)bias)[lane];
        float vx = (acc.x + exs * hdv.x) / dtot + b2.x;
        float vy = (acc.y + exs * hdv.y) / dtot + b2.y;
        vx = (vx > 0.f) ? vx : expm1f(vx);
        vy = (vy > 0.f) ? vy : expm1f(vy);
        ((float2*)out)[d * 64 + lane] = make_float2(vx, vy);
    }
}

extern "C" void kernel_launch(void* const* d_in, const int* in_sizes, int n_in,
                              void* d_out, int out_size, void* d_ws, size_t ws_size,
                              hipStream_t stream) {
    const float* x     = (const float*)d_in[0];
    const int*   ei    = (const int*)d_in[1];
    const float* W     = (const float*)d_in[2];
    const float* att_s = (const float*)d_in[3];
    const float* att_d = (const float*)d_in[4];
    const float* bias  = (const float*)d_in[5];
    float* out = (float*)d_out;

    // workspace layout (~20.07 MB)
    unsigned int* h_bf = (unsigned int*)d_ws;                   // 12.8 MB
    float* asrc = (float*)(h_bf + (size_t)N_NODES * 64);        // 1.6 MB
    float* adst = asrc + (size_t)N_NODES * HEADS;               // 1.6 MB
    unsigned int* bin = (unsigned int*)(adst + (size_t)N_NODES * HEADS); // 4.0 MB
    unsigned int* wfrag = bin + (size_t)NBUCK * BCAP;           // 64 KB (16B-aligned)
    int* cnt = (int*)(wfrag + 16384);                           // 782 ints

    hipMemsetAsync(cnt, 0, NBUCK * sizeof(int), stream);
    k_prepW<<<4, 512, 0, stream>>>(W, wfrag);
    k_gemm<<<(N_NODES + 127) / 128, 512, 0, stream>>>(x, wfrag, att_s, att_d,
                                                      h_bf, asrc, adst);
    k_bin<<<BINB, 512, 0, stream>>>(ei, cnt, bin);
    k_aggr<<<NBUCK, 512, 0, stream>>>(h_bf, bin, cnt, asrc, adst, bias, out);
}

// Round 15
// 161.328 us; speedup vs baseline: 1.2795x; 1.0622x over previous
//
#include <hip/hip_runtime.h>

#define N_NODES 50000
#define N_EDGES 800000
#define HEADS 8
#define NEG_SLOPE 0.2f
#define EPS 1e-16f
#define NBUCK 782            // ceil(50000/64) buckets of 64 dst nodes
#define BNODES 64
#define BCAP 1280            // bucket capacity (load ~Poisson(1024); +8 sigma)
#define GEMMB 391            // gemm blocks (128 rows each)
#define BINB 250             // bin blocks (first in grid)
#define EPB 3200             // 800000 / 250 edges per bin block
#define LOG2E 1.4426950408889634f

typedef __bf16 bf16x8 __attribute__((ext_vector_type(8)));
typedef float f32x4 __attribute__((ext_vector_type(4)));

// bf16x2 pack/unpack (RNE), exact unpack
__device__ inline unsigned int f2_to_bf2(float a, float b) {
    unsigned int ua = __float_as_uint(a);
    unsigned int ub = __float_as_uint(b);
    ua += 0x7fff + ((ua >> 16) & 1);
    ub += 0x7fff + ((ub >> 16) & 1);
    return (ua >> 16) | (ub & 0xffff0000u);
}
__device__ inline float2 bf2_to_f2(unsigned int u) {
    return make_float2(__uint_as_float(u << 16),
                       __uint_as_float(u & 0xffff0000u));
}

// ---------------------------------------------------------------------------
// Kernel 0: one-shot fragment prep, split precision (hi=bf16(v),
// lo=bf16(v-hi)). Main W fragments: (kstep,n,lane,e) k=kstep*32+(l>>4)*8+e,
// col=n*16+(l&15). r14 BUG FIX: the logit operand must be C2 = W @ B2
// (so x·C2 = (x·W)·B2 = h·att by associativity), NOT B2 itself — r14 fed
// x into h's attention product. C2[k][n2] = sum_c W[k][(n2&7)*16+c] *
// att[n2&7][c], att = att_s for n2<8 else att_d; computed here in fp32.
// Layout in wfrag (uint4 units): Whi [0,2048) Wlo [2048,4096)
// C2hi [4096,4352) C2lo [4352,4608).
// ---------------------------------------------------------------------------
__global__ __launch_bounds__(512) void k_prepW(const float* __restrict__ W,
                                               const float* __restrict__ att_s,
                                               const float* __restrict__ att_d,
                                               unsigned int* __restrict__ wfrag) {
    const int t = blockIdx.x * 512 + threadIdx.x;
    if (t >= 2048) return;
    const int lane = t & 63;
    uint4* dst = (uint4*)wfrag;

    {   // main W fragments
        const int n = (t >> 6) & 7;
        const int kstep = t >> 9;
        const int c = n * 16 + (lane & 15);
        const int kb = kstep * 32 + (lane >> 4) * 8;
        unsigned int hi[8], lo[8];
#pragma unroll
        for (int e = 0; e < 8; ++e) {
            const float v = W[(kb + e) * 128 + c];
            const __bf16 h = (__bf16)v;
            const __bf16 l = (__bf16)(v - (float)h);
            hi[e] = (unsigned int)__builtin_bit_cast(unsigned short, h);
            lo[e] = (unsigned int)__builtin_bit_cast(unsigned short, l);
        }
        uint4 ph, pl;
        ph.x = hi[0] | (hi[1] << 16); ph.y = hi[2] | (hi[3] << 16);
        ph.z = hi[4] | (hi[5] << 16); ph.w = hi[6] | (hi[7] << 16);
        pl.x = lo[0] | (lo[1] << 16); pl.y = lo[2] | (lo[3] << 16);
        pl.z = lo[4] | (lo[5] << 16); pl.w = lo[6] | (lo[7] << 16);
        dst[t] = ph;
        dst[2048 + t] = pl;
    }

    if (t < 256) {   // C2 = W @ B2 fragments (ks = t>>6, lane)
        const int ks = t >> 6;
        const int n2 = lane & 15;
        const int kb = ks * 32 + (lane >> 4) * 8;
        const int head = n2 & 7;
        const float* av = (n2 < 8) ? (att_s + head * 16) : (att_d + head * 16);
        const int cb = head * 16;            // W column base for this head
        unsigned int hi[8], lo[8];
#pragma unroll
        for (int e = 0; e < 8; ++e) {
            const int k = kb + e;
            float v = 0.f;
#pragma unroll
            for (int c = 0; c < 16; ++c)
                v += W[k * 128 + cb + c] * av[c];
            const __bf16 h = (__bf16)v;
            const __bf16 l = (__bf16)(v - (float)h);
            hi[e] = (unsigned int)__builtin_bit_cast(unsigned short, h);
            lo[e] = (unsigned int)__builtin_bit_cast(unsigned short, l);
        }
        uint4 ph, pl;
        ph.x = hi[0] | (hi[1] << 16); ph.y = hi[2] | (hi[3] << 16);
        ph.z = hi[4] | (hi[5] << 16); ph.w = hi[6] | (hi[7] << 16);
        pl.x = lo[0] | (lo[1] << 16); pl.y = lo[2] | (lo[3] << 16);
        pl.z = lo[4] | (lo[5] << 16); pl.w = lo[6] | (lo[7] << 16);
        dst[4096 + t] = ph;
        dst[4352 + t] = pl;
    }
}

// LDS union: gemm path 72 KB fragments; bin path ~25.3 KB. 2 blocks/CU.
union SMem {
    uint4 w[4608];                        // 72 KB
    struct {
        unsigned int srt[EPB];            // 12.8 KB
        int hist[NBUCK];
        int base[NBUCK];
        int cur[NBUCK];
        int gbase[NBUCK];
        int wsum[8];
    } b;
};

// ---------------------------------------------------------------------------
// Fused kernel. Blocks [0,BINB) bin edges; [BINB,BINB+GEMMB) run the MFMA
// GEMM. The session-long ~45-55us gemm invariant was the EPILOGUE — 288
// cross-lane shuffle ops/wave on the one-per-CU LDS pipe shared by 16
// waves. Fix: logits via an extra MFMA chain on C2 = W@B2 (x·C2 = h·att),
// same verified D-layout -> asrc in lanes m<8, adst in m>=8, zero
// shuffles. Epilogue cross-lane ops 288 -> 32 (h-pack pairing only).
// ---------------------------------------------------------------------------
__global__ __launch_bounds__(512) void k_fused(const float* __restrict__ x,
                                               const unsigned int* __restrict__ wfrag,
                                               const int* __restrict__ ei,
                                               unsigned int* __restrict__ h_bf,
                                               float* __restrict__ asrc,
                                               float* __restrict__ adst,
                                               int* __restrict__ cnt,
                                               unsigned int* __restrict__ bin) {
    __shared__ SMem sm;
    const int tid = threadIdx.x;

    if (blockIdx.x >= BINB) {
        // ------------------------- GEMM path -------------------------
        // stage all fragments -> LDS (4608 uint4, 9 per thread)
#pragma unroll
        for (int i = 0; i < 9; ++i)
            sm.w[i * 512 + tid] = ((const uint4*)wfrag)[i * 512 + tid];
        __syncthreads();

        const int w = tid >> 6;           // 0..7, wave -> 16-row strip
        const int l = tid & 63;
        const int m = l & 15;             // A-row; also logit column n2
        const int g = l >> 4;             // k-group
        const int row0 = (blockIdx.x - BINB) * 128 + w * 16;
        const int rowa = row0 + m;
        const int rowc = (rowa < N_NODES) ? rowa : (N_NODES - 1);
        const float* xrow = x + (size_t)rowc * 128 + g * 8;

        f32x4 acc[8];
#pragma unroll
        for (int n = 0; n < 8; ++n) acc[n] = (f32x4){0.f, 0.f, 0.f, 0.f};
        f32x4 acc2 = (f32x4){0.f, 0.f, 0.f, 0.f};

        const bf16x8* Lhi = (const bf16x8*)sm.w;
        const bf16x8* Llo = Lhi + 2048;
        const bf16x8* Chi = Lhi + 4096;
        const bf16x8* Clo = Lhi + 4352;

#pragma unroll
        for (int ks = 0; ks < 4; ++ks) {
            const float4 xa = *(const float4*)(xrow + ks * 32);
            const float4 xb = *(const float4*)(xrow + ks * 32 + 4);
            const float xv[8] = {xa.x, xa.y, xa.z, xa.w, xb.x, xb.y, xb.z, xb.w};
            bf16x8 ahi, alo;
#pragma unroll
            for (int e = 0; e < 8; ++e) {
                const __bf16 h = (__bf16)xv[e];
                ahi[e] = h;
                alo[e] = (__bf16)(xv[e] - (float)h);
            }
#pragma unroll
            for (int n = 0; n < 8; ++n) {
                const bf16x8 bh = Lhi[(ks * 8 + n) * 64 + l];
                const bf16x8 bl = Llo[(ks * 8 + n) * 64 + l];
                acc[n] = __builtin_amdgcn_mfma_f32_16x16x32_bf16(ahi, bh, acc[n], 0, 0, 0);
                acc[n] = __builtin_amdgcn_mfma_f32_16x16x32_bf16(alo, bh, acc[n], 0, 0, 0);
                acc[n] = __builtin_amdgcn_mfma_f32_16x16x32_bf16(ahi, bl, acc[n], 0, 0, 0);
            }
            {   // logits: x @ C2 = (x@W)@B2 (asrc cols 0-7, adst cols 8-15)
                const bf16x8 bh = Chi[ks * 64 + l];
                const bf16x8 bl = Clo[ks * 64 + l];
                acc2 = __builtin_amdgcn_mfma_f32_16x16x32_bf16(ahi, bh, acc2, 0, 0, 0);
                acc2 = __builtin_amdgcn_mfma_f32_16x16x32_bf16(alo, bh, acc2, 0, 0, 0);
                acc2 = __builtin_amdgcn_mfma_f32_16x16x32_bf16(ahi, bl, acc2, 0, 0, 0);
            }
        }

        // Epilogue, shuffle-free logits. Lane l holds D[g*4+r][.. m ..].
#pragma unroll
        for (int r = 0; r < 4; ++r) {
            const int rowr = row0 + g * 4 + r;
            if (rowr < N_NODES) {
                if (m < 8) asrc[rowr * 8 + m] = acc2[r] * LOG2E;
                else       adst[rowr * 8 + (m - 8)] = acc2[r] * LOG2E;
            }
        }
#pragma unroll
        for (int n = 0; n < 8; ++n) {
#pragma unroll
            for (int r = 0; r < 4; ++r) {
                const int rowr = row0 + g * 4 + r;
                const float hv = acc[n][r];
                const float hp = __shfl_xor(hv, 1);   // odd-channel partner
                if (rowr < N_NODES && !(m & 1))
                    h_bf[(size_t)rowr * 64 + n * 8 + (m >> 1)] = f2_to_bf2(hv, hp);
            }
        }
    } else {
        // ------------------------- BIN path -------------------------
        const int e0 = blockIdx.x * EPB;
        const int lane = tid & 63;
        const int wid = tid >> 6;

        for (int b = tid; b < NBUCK; b += 512) sm.b.hist[b] = 0;
        __syncthreads();

        for (int i = tid; i < EPB; i += 512)
            atomicAdd(&sm.b.hist[ei[N_EDGES + e0 + i] >> 6], 1);
        __syncthreads();

        const int b2 = tid * 2;
        const int l0 = (b2     < NBUCK) ? sm.b.hist[b2]     : 0;
        const int l1 = (b2 + 1 < NBUCK) ? sm.b.hist[b2 + 1] : 0;
        const int tot = l0 + l1;
        int inc = tot;
#pragma unroll
        for (int off = 1; off < 64; off <<= 1) {
            const int u = __shfl_up(inc, off);
            if (lane >= off) inc += u;
        }
        if (lane == 63) sm.b.wsum[wid] = inc;
        __syncthreads();
        int run = inc - tot;
        for (int w2 = 0; w2 < wid; ++w2) run += sm.b.wsum[w2];
        if (b2     < NBUCK) { sm.b.base[b2]     = run; sm.b.cur[b2]     = run; } run += l0;
        if (b2 + 1 < NBUCK) { sm.b.base[b2 + 1] = run; sm.b.cur[b2 + 1] = run; }
        __syncthreads();

        for (int i = tid; i < EPB; i += 512) {
            const unsigned src = (unsigned)ei[e0 + i];
            const unsigned dst = (unsigned)ei[N_EDGES + e0 + i];
            const int p = atomicAdd(&sm.b.cur[dst >> 6], 1);
            if ((unsigned)p < (unsigned)EPB) sm.b.srt[p] = (dst << 16) | src;
        }
        __syncthreads();

        for (int b = tid; b < NBUCK; b += 512)
            sm.b.gbase[b] = (sm.b.hist[b] > 0) ? atomicAdd(&cnt[b], sm.b.hist[b]) : 0;
        __syncthreads();

        for (int p = tid; p < EPB; p += 512) {
            const unsigned rec = sm.b.srt[p];
            const int b = rec >> 22;
            if (b < NBUCK) {
                const int pos = sm.b.gbase[b] + (p - sm.b.base[b]);
                if ((unsigned)pos < (unsigned)BCAP)
                    bin[(size_t)b * BCAP + pos] = rec;
            }
        }
    }
}

// ---------------------------------------------------------------------------
// Kernel 3: aggregation (r5 proven version, ~53us; near its random-gather
// path bound). One block (8 waves) per bucket; counting sort; clamped
// depth-16 batches; producer/consumer ex via shfl.
// ---------------------------------------------------------------------------
__global__ __launch_bounds__(512) void k_aggr(const unsigned int* __restrict__ h_bf,
                                              const unsigned int* __restrict__ bin,
                                              const int* __restrict__ cnt,
                                              const float* __restrict__ asrc,
                                              const float* __restrict__ adst,
                                              const float* __restrict__ bias,
                                              float* __restrict__ out) {
    __shared__ unsigned int srt[BCAP];    // 5.0 KB
    __shared__ int hist[BNODES], base[BNODES], scn[BNODES];

    const int bkt = blockIdx.x;
    const int tid = threadIdx.x;
    const int wid = tid >> 6;
    const int lane = tid & 63;
    const int hd = lane >> 3;     // consumer head (channels lane*2, lane*2+1)
    const int eslot = lane >> 3;  // producer edge slot 0..7
    const int phead = lane & 7;   // producer head

    const int cntb = min(cnt[bkt], BCAP);
    const unsigned int* seg = bin + (size_t)bkt * BCAP;

    if (tid < BNODES) hist[tid] = 0;
    __syncthreads();

    unsigned int myrec[3];
    int myrank[3];
    int nrec = 0;
    for (int i = tid; i < cntb; i += 512) {
        const unsigned rec = seg[i];
        myrank[nrec] = atomicAdd(&hist[(rec >> 16) & 63], 1);
        myrec[nrec] = rec;
        ++nrec;
    }
    __syncthreads();

    if (tid < BNODES) scn[tid] = hist[tid];
    __syncthreads();
    for (int off = 1; off < BNODES; off <<= 1) {
        int v = 0;
        if (tid < BNODES && tid >= off) v = scn[tid - off];
        __syncthreads();
        if (tid < BNODES) scn[tid] += v;
        __syncthreads();
    }
    if (tid < BNODES) base[tid] = scn[tid] - hist[tid];
    __syncthreads();

    for (int k = 0; k < nrec; ++k) {
        const unsigned rec = myrec[k];
        const int p = base[(rec >> 16) & 63] + myrank[k];
        if ((unsigned)p < (unsigned)BCAP) srt[p] = rec;
    }
    __syncthreads();

    for (int dl = wid; dl < BNODES; dl += 8) {
        const int d = bkt * BNODES + dl;
        if (d >= N_NODES) continue;
        const int jb = base[dl];
        const int jn = hist[dl];

        const float adst_h = adst[d * 8 + hd];      // consumer head
        const float adst_p = adst[d * 8 + phead];   // producer head
        const float asrc_self = asrc[d * 8 + hd];
        const float2 hdv = bf2_to_f2(h_bf[d * 64 + lane]);

        float es = asrc_self + adst_h;
        es = fmaxf(es, NEG_SLOPE * es);       // LeakyReLU, slope<1
        const float exs = exp2f(es);          // logits pre-scaled by log2e

        float2 acc = make_float2(0.f, 0.f);
        float den = 0.f;

        for (int j0 = 0; j0 < jn; j0 += 16) {
            int s[16];
#pragma unroll
            for (int i = 0; i < 16; ++i) {
                const int jj = j0 + i;
                s[i] = (int)(srt[jb + ((jj < jn) ? jj : jn - 1)] & 0xffffu);
            }
            unsigned int hv[16];
#pragma unroll
            for (int i = 0; i < 16; ++i) hv[i] = h_bf[s[i] * 64 + lane];

            const int ia = j0 + eslot;
            const int ib = ia + 8;
            const int sa = (int)(srt[jb + min(ia, jn - 1)] & 0xffffu);
            const int sb = (int)(srt[jb + min(ib, jn - 1)] & 0xffffu);
            float eA = asrc[sa * 8 + phead] + adst_p;
            float eB = asrc[sb * 8 + phead] + adst_p;
            eA = fmaxf(eA, NEG_SLOPE * eA);
            eB = fmaxf(eB, NEG_SLOPE * eB);
            const float exA = (ia < jn) ? exp2f(eA) : 0.f;
            const float exB = (ib < jn) ? exp2f(eB) : 0.f;

#pragma unroll
            for (int i = 0; i < 16; ++i) {
                const float ex = __shfl((i < 8) ? exA : exB,
                                        ((i & 7) << 3) | hd, 64);
                const float2 hv2 = bf2_to_f2(hv[i]);
                acc.x += ex * hv2.x;
                acc.y += ex * hv2.y;
                den += ex;
            }
        }

        const float dtot = den + exs + EPS;
        const float2 b2 = ((const float2*)bias)[lane];
        float vx = (acc.x + exs * hdv.x) / dtot + b2.x;
        float vy = (acc.y + exs * hdv.y) / dtot + b2.y;
        vx = (vx > 0.f) ? vx : expm1f(vx);
        vy = (vy > 0.f) ? vy : expm1f(vy);
        ((float2*)out)[d * 64 + lane] = make_float2(vx, vy);
    }
}

extern "C" void kernel_launch(void* const* d_in, const int* in_sizes, int n_in,
                              void* d_out, int out_size, void* d_ws, size_t ws_size,
                              hipStream_t stream) {
    const float* x     = (const float*)d_in[0];
    const int*   ei    = (const int*)d_in[1];
    const float* W     = (const float*)d_in[2];
    const float* att_s = (const float*)d_in[3];
    const float* att_d = (const float*)d_in[4];
    const float* bias  = (const float*)d_in[5];
    float* out = (float*)d_out;

    // workspace layout (~20.1 MB)
    unsigned int* h_bf = (unsigned int*)d_ws;                   // 12.8 MB
    float* asrc = (float*)(h_bf + (size_t)N_NODES * 64);        // 1.6 MB
    float* adst = asrc + (size_t)N_NODES * HEADS;               // 1.6 MB
    unsigned int* bin = (unsigned int*)(adst + (size_t)N_NODES * HEADS); // 4.0 MB
    unsigned int* wfrag = bin + (size_t)NBUCK * BCAP;           // 73.7 KB (16B-aligned)
    int* cnt = (int*)(wfrag + 18432);                           // 782 ints

    hipMemsetAsync(cnt, 0, NBUCK * sizeof(int), stream);
    k_prepW<<<4, 512, 0, stream>>>(W, att_s, att_d, wfrag);
    k_fused<<<BINB + GEMMB, 512, 0, stream>>>(x, wfrag, ei,
                                              h_bf, asrc, adst, cnt, bin);
    k_aggr<<<NBUCK, 512, 0, stream>>>(h_bf, bin, cnt, asrc, adst, bias, out);
}

// Round 16
// 154.346 us; speedup vs baseline: 1.3374x; 1.0452x over previous
//
#include <hip/hip_runtime.h>

#define N_NODES 50000
#define N_EDGES 800000
#define HEADS 8
#define NEG_SLOPE 0.2f
#define EPS 1e-16f
#define NBUCK 782            // ceil(50000/64) buckets of 64 dst nodes
#define BNODES 64
#define BCAP 1280            // bucket capacity (load ~Poisson(1024); +8 sigma)
#define GEMMB 391            // gemm blocks (128 rows each)
#define BINB 250             // bin blocks (first in grid)
#define EPB 3200             // 800000 / 250 edges per bin block
#define LOG2E 1.4426950408889634f

typedef __bf16 bf16x8 __attribute__((ext_vector_type(8)));
typedef float f32x4 __attribute__((ext_vector_type(4)));

// bf16x2 pack/unpack (RNE), exact unpack
__device__ inline unsigned int f2_to_bf2(float a, float b) {
    unsigned int ua = __float_as_uint(a);
    unsigned int ub = __float_as_uint(b);
    ua += 0x7fff + ((ua >> 16) & 1);
    ub += 0x7fff + ((ub >> 16) & 1);
    return (ua >> 16) | (ub & 0xffff0000u);
}
__device__ inline float2 bf2_to_f2(unsigned int u) {
    return make_float2(__uint_as_float(u << 16),
                       __uint_as_float(u & 0xffff0000u));
}

// ---------------------------------------------------------------------------
// Kernel 0: one-shot fragment prep. r16 change: W is stored hi-ONLY
// (h = x·W_hi; the dropped x·W_lo term is ~1e-3 std, an order below the
// bf16-h quantization already dominating absmax). C2 = W @ B2 keeps the
// full fp32 build + hi/lo split (logits stay ~fp32-exact).
// Fragment (kstep,n,lane,e): k=kstep*32+(l>>4)*8+e, col=n*16+(l&15).
// wfrag layout (uint4 units): Whi [0,2048) C2hi [2048,2304) C2lo [2304,2560).
// ---------------------------------------------------------------------------
__global__ __launch_bounds__(512) void k_prepW(const float* __restrict__ W,
                                               const float* __restrict__ att_s,
                                               const float* __restrict__ att_d,
                                               unsigned int* __restrict__ wfrag) {
    const int t = blockIdx.x * 512 + threadIdx.x;
    if (t >= 2048) return;
    const int lane = t & 63;
    uint4* dst = (uint4*)wfrag;

    {   // main W fragments (hi only)
        const int n = (t >> 6) & 7;
        const int kstep = t >> 9;
        const int c = n * 16 + (lane & 15);
        const int kb = kstep * 32 + (lane >> 4) * 8;
        unsigned int hi[8];
#pragma unroll
        for (int e = 0; e < 8; ++e) {
            const float v = W[(kb + e) * 128 + c];
            const __bf16 h = (__bf16)v;
            hi[e] = (unsigned int)__builtin_bit_cast(unsigned short, h);
        }
        uint4 ph;
        ph.x = hi[0] | (hi[1] << 16); ph.y = hi[2] | (hi[3] << 16);
        ph.z = hi[4] | (hi[5] << 16); ph.w = hi[6] | (hi[7] << 16);
        dst[t] = ph;
    }

    if (t < 256) {   // C2 = W @ B2 fragments (ks = t>>6, lane), hi/lo split
        const int ks = t >> 6;
        const int n2 = lane & 15;
        const int kb = ks * 32 + (lane >> 4) * 8;
        const int head = n2 & 7;
        const float* av = (n2 < 8) ? (att_s + head * 16) : (att_d + head * 16);
        const int cb = head * 16;            // W column base for this head
        unsigned int hi[8], lo[8];
#pragma unroll
        for (int e = 0; e < 8; ++e) {
            const int k = kb + e;
            float v = 0.f;
#pragma unroll
            for (int c = 0; c < 16; ++c)
                v += W[k * 128 + cb + c] * av[c];
            const __bf16 h = (__bf16)v;
            const __bf16 l = (__bf16)(v - (float)h);
            hi[e] = (unsigned int)__builtin_bit_cast(unsigned short, h);
            lo[e] = (unsigned int)__builtin_bit_cast(unsigned short, l);
        }
        uint4 ph, pl;
        ph.x = hi[0] | (hi[1] << 16); ph.y = hi[2] | (hi[3] << 16);
        ph.z = hi[4] | (hi[5] << 16); ph.w = hi[6] | (hi[7] << 16);
        pl.x = lo[0] | (lo[1] << 16); pl.y = lo[2] | (lo[3] << 16);
        pl.z = lo[4] | (lo[5] << 16); pl.w = lo[6] | (lo[7] << 16);
        dst[2048 + t] = ph;
        dst[2304 + t] = pl;
    }
}

// LDS union: gemm path 40 KB fragments; bin path ~25.3 KB. 4 blocks/CU
// (was 72 KB -> 2/CU in r15; that LDS footprint halved both co-residency
// and doubled the per-CU ds_read load).
union SMem {
    uint4 w[2560];                        // 40 KB
    struct {
        unsigned int srt[EPB];            // 12.8 KB
        int hist[NBUCK];
        int base[NBUCK];
        int cur[NBUCK];
        int gbase[NBUCK];
        int wsum[8];
    } b;
};

// ---------------------------------------------------------------------------
// Fused kernel. Blocks [0,BINB) bin edges; [BINB,BINB+GEMMB) run the MFMA
// GEMM (shuffle-free logits via the C2 chain; r15-proven). r16: 2-term W
// product (hi only) — ds_reads 72->40/wave, MFMAs 108->76/wave, LDS 40KB
// -> 4 blocks/CU.
// ---------------------------------------------------------------------------
__global__ __launch_bounds__(512) void k_fused(const float* __restrict__ x,
                                               const unsigned int* __restrict__ wfrag,
                                               const int* __restrict__ ei,
                                               unsigned int* __restrict__ h_bf,
                                               float* __restrict__ asrc,
                                               float* __restrict__ adst,
                                               int* __restrict__ cnt,
                                               unsigned int* __restrict__ bin) {
    __shared__ SMem sm;
    const int tid = threadIdx.x;

    if (blockIdx.x >= BINB) {
        // ------------------------- GEMM path -------------------------
        // stage fragments -> LDS (2560 uint4, 5 per thread)
#pragma unroll
        for (int i = 0; i < 5; ++i)
            sm.w[i * 512 + tid] = ((const uint4*)wfrag)[i * 512 + tid];
        __syncthreads();

        const int w = tid >> 6;           // 0..7, wave -> 16-row strip
        const int l = tid & 63;
        const int m = l & 15;             // A-row; also logit column n2
        const int g = l >> 4;             // k-group
        const int row0 = (blockIdx.x - BINB) * 128 + w * 16;
        const int rowa = row0 + m;
        const int rowc = (rowa < N_NODES) ? rowa : (N_NODES - 1);
        const float* xrow = x + (size_t)rowc * 128 + g * 8;

        f32x4 acc[8];
#pragma unroll
        for (int n = 0; n < 8; ++n) acc[n] = (f32x4){0.f, 0.f, 0.f, 0.f};
        f32x4 acc2 = (f32x4){0.f, 0.f, 0.f, 0.f};

        const bf16x8* Lhi = (const bf16x8*)sm.w;
        const bf16x8* Chi = Lhi + 2048;
        const bf16x8* Clo = Lhi + 2304;

#pragma unroll
        for (int ks = 0; ks < 4; ++ks) {
            const float4 xa = *(const float4*)(xrow + ks * 32);
            const float4 xb = *(const float4*)(xrow + ks * 32 + 4);
            const float xv[8] = {xa.x, xa.y, xa.z, xa.w, xb.x, xb.y, xb.z, xb.w};
            bf16x8 ahi, alo;
#pragma unroll
            for (int e = 0; e < 8; ++e) {
                const __bf16 h = (__bf16)xv[e];
                ahi[e] = h;
                alo[e] = (__bf16)(xv[e] - (float)h);
            }
#pragma unroll
            for (int n = 0; n < 8; ++n) {
                const bf16x8 bh = Lhi[(ks * 8 + n) * 64 + l];
                acc[n] = __builtin_amdgcn_mfma_f32_16x16x32_bf16(ahi, bh, acc[n], 0, 0, 0);
                acc[n] = __builtin_amdgcn_mfma_f32_16x16x32_bf16(alo, bh, acc[n], 0, 0, 0);
            }
            {   // logits: x @ C2 = x@W@B2 (asrc cols 0-7, adst cols 8-15)
                const bf16x8 bh = Chi[ks * 64 + l];
                const bf16x8 bl = Clo[ks * 64 + l];
                acc2 = __builtin_amdgcn_mfma_f32_16x16x32_bf16(ahi, bh, acc2, 0, 0, 0);
                acc2 = __builtin_amdgcn_mfma_f32_16x16x32_bf16(alo, bh, acc2, 0, 0, 0);
                acc2 = __builtin_amdgcn_mfma_f32_16x16x32_bf16(ahi, bl, acc2, 0, 0, 0);
            }
        }

        // Epilogue, shuffle-free logits. Lane l holds D[g*4+r][.. m ..].
#pragma unroll
        for (int r = 0; r < 4; ++r) {
            const int rowr = row0 + g * 4 + r;
            if (rowr < N_NODES) {
                if (m < 8) asrc[rowr * 8 + m] = acc2[r] * LOG2E;
                else       adst[rowr * 8 + (m - 8)] = acc2[r] * LOG2E;
            }
        }
#pragma unroll
        for (int n = 0; n < 8; ++n) {
#pragma unroll
            for (int r = 0; r < 4; ++r) {
                const int rowr = row0 + g * 4 + r;
                const float hv = acc[n][r];
                const float hp = __shfl_xor(hv, 1);   // odd-channel partner
                if (rowr < N_NODES && !(m & 1))
                    h_bf[(size_t)rowr * 64 + n * 8 + (m >> 1)] = f2_to_bf2(hv, hp);
            }
        }
    } else {
        // ------------------------- BIN path -------------------------
        const int e0 = blockIdx.x * EPB;
        const int lane = tid & 63;
        const int wid = tid >> 6;

        for (int b = tid; b < NBUCK; b += 512) sm.b.hist[b] = 0;
        __syncthreads();

        for (int i = tid; i < EPB; i += 512)
            atomicAdd(&sm.b.hist[ei[N_EDGES + e0 + i] >> 6], 1);
        __syncthreads();

        const int b2 = tid * 2;
        const int l0 = (b2     < NBUCK) ? sm.b.hist[b2]     : 0;
        const int l1 = (b2 + 1 < NBUCK) ? sm.b.hist[b2 + 1] : 0;
        const int tot = l0 + l1;
        int inc = tot;
#pragma unroll
        for (int off = 1; off < 64; off <<= 1) {
            const int u = __shfl_up(inc, off);
            if (lane >= off) inc += u;
        }
        if (lane == 63) sm.b.wsum[wid] = inc;
        __syncthreads();
        int run = inc - tot;
        for (int w2 = 0; w2 < wid; ++w2) run += sm.b.wsum[w2];
        if (b2     < NBUCK) { sm.b.base[b2]     = run; sm.b.cur[b2]     = run; } run += l0;
        if (b2 + 1 < NBUCK) { sm.b.base[b2 + 1] = run; sm.b.cur[b2 + 1] = run; }
        __syncthreads();

        for (int i = tid; i < EPB; i += 512) {
            const unsigned src = (unsigned)ei[e0 + i];
            const unsigned dst = (unsigned)ei[N_EDGES + e0 + i];
            const int p = atomicAdd(&sm.b.cur[dst >> 6], 1);
            if ((unsigned)p < (unsigned)EPB) sm.b.srt[p] = (dst << 16) | src;
        }
        __syncthreads();

        for (int b = tid; b < NBUCK; b += 512)
            sm.b.gbase[b] = (sm.b.hist[b] > 0) ? atomicAdd(&cnt[b], sm.b.hist[b]) : 0;
        __syncthreads();

        for (int p = tid; p < EPB; p += 512) {
            const unsigned rec = sm.b.srt[p];
            const int b = rec >> 22;
            if (b < NBUCK) {
                const int pos = sm.b.gbase[b] + (p - sm.b.base[b]);
                if ((unsigned)pos < (unsigned)BCAP)
                    bin[(size_t)b * BCAP + pos] = rec;
            }
        }
    }
}

// ---------------------------------------------------------------------------
// Kernel 3: aggregation (r5 proven version, ~53.8us; near its random-gather
// memory-system bound — FETCH 108MB at ~2.5TB/s effective, VALUBusy ~62%).
// One block (8 waves) per bucket; counting sort; clamped depth-16 batches;
// producer/consumer ex via shfl.
// ---------------------------------------------------------------------------
__global__ __launch_bounds__(512) void k_aggr(const unsigned int* __restrict__ h_bf,
                                              const unsigned int* __restrict__ bin,
                                              const int* __restrict__ cnt,
                                              const float* __restrict__ asrc,
                                              const float* __restrict__ adst,
                                              const float* __restrict__ bias,
                                              float* __restrict__ out) {
    __shared__ unsigned int srt[BCAP];    // 5.0 KB
    __shared__ int hist[BNODES], base[BNODES], scn[BNODES];

    const int bkt = blockIdx.x;
    const int tid = threadIdx.x;
    const int wid = tid >> 6;
    const int lane = tid & 63;
    const int hd = lane >> 3;     // consumer head (channels lane*2, lane*2+1)
    const int eslot = lane >> 3;  // producer edge slot 0..7
    const int phead = lane & 7;   // producer head

    const int cntb = min(cnt[bkt], BCAP);
    const unsigned int* seg = bin + (size_t)bkt * BCAP;

    if (tid < BNODES) hist[tid] = 0;
    __syncthreads();

    unsigned int myrec[3];
    int myrank[3];
    int nrec = 0;
    for (int i = tid; i < cntb; i += 512) {
        const unsigned rec = seg[i];
        myrank[nrec] = atomicAdd(&hist[(rec >> 16) & 63], 1);
        myrec[nrec] = rec;
        ++nrec;
    }
    __syncthreads();

    if (tid < BNODES) scn[tid] = hist[tid];
    __syncthreads();
    for (int off = 1; off < BNODES; off <<= 1) {
        int v = 0;
        if (tid < BNODES && tid >= off) v = scn[tid - off];
        __syncthreads();
        if (tid < BNODES) scn[tid] += v;
        __syncthreads();
    }
    if (tid < BNODES) base[tid] = scn[tid] - hist[tid];
    __syncthreads();

    for (int k = 0; k < nrec; ++k) {
        const unsigned rec = myrec[k];
        const int p = base[(rec >> 16) & 63] + myrank[k];
        if ((unsigned)p < (unsigned)BCAP) srt[p] = rec;
    }
    __syncthreads();

    for (int dl = wid; dl < BNODES; dl += 8) {
        const int d = bkt * BNODES + dl;
        if (d >= N_NODES) continue;
        const int jb = base[dl];
        const int jn = hist[dl];

        const float adst_h = adst[d * 8 + hd];      // consumer head
        const float adst_p = adst[d * 8 + phead];   // producer head
        const float asrc_self = asrc[d * 8 + hd];
        const float2 hdv = bf2_to_f2(h_bf[d * 64 + lane]);

        float es = asrc_self + adst_h;
        es = fmaxf(es, NEG_SLOPE * es);       // LeakyReLU, slope<1
        const float exs = exp2f(es);          // logits pre-scaled by log2e

        float2 acc = make_float2(0.f, 0.f);
        float den = 0.f;

        for (int j0 = 0; j0 < jn; j0 += 16) {
            int s[16];
#pragma unroll
            for (int i = 0; i < 16; ++i) {
                const int jj = j0 + i;
                s[i] = (int)(srt[jb + ((jj < jn) ? jj : jn - 1)] & 0xffffu);
            }
            unsigned int hv[16];
#pragma unroll
            for (int i = 0; i < 16; ++i) hv[i] = h_bf[s[i] * 64 + lane];

            const int ia = j0 + eslot;
            const int ib = ia + 8;
            const int sa = (int)(srt[jb + min(ia, jn - 1)] & 0xffffu);
            const int sb = (int)(srt[jb + min(ib, jn - 1)] & 0xffffu);
            float eA = asrc[sa * 8 + phead] + adst_p;
            float eB = asrc[sb * 8 + phead] + adst_p;
            eA = fmaxf(eA, NEG_SLOPE * eA);
            eB = fmaxf(eB, NEG_SLOPE * eB);
            const float exA = (ia < jn) ? exp2f(eA) : 0.f;
            const float exB = (ib < jn) ? exp2f(eB) : 0.f;

#pragma unroll
            for (int i = 0; i < 16; ++i) {
                const float ex = __shfl((i < 8) ? exA : exB,
                                        ((i & 7) << 3) | hd, 64);
                const float2 hv2 = bf2_to_f2(hv[i]);
                acc.x += ex * hv2.x;
                acc.y += ex * hv2.y;
                den += ex;
            }
        }

        const float dtot = den + exs + EPS;
        const float2 b2 = ((const float2*)bias)[lane];
        float vx = (acc.x + exs * hdv.x) / dtot + b2.x;
        float vy = (acc.y + exs * hdv.y) / dtot + b2.y;
        vx = (vx > 0.f) ? vx : expm1f(vx);
        vy = (vy > 0.f) ? vy : expm1f(vy);
        ((float2*)out)[d * 64 + lane] = make_float2(vx, vy);
    }
}

extern "C" void kernel_launch(void* const* d_in, const int* in_sizes, int n_in,
                              void* d_out, int out_size, void* d_ws, size_t ws_size,
                              hipStream_t stream) {
    const float* x     = (const float*)d_in[0];
    const int*   ei    = (const int*)d_in[1];
    const float* W     = (const float*)d_in[2];
    const float* att_s = (const float*)d_in[3];
    const float* att_d = (const float*)d_in[4];
    const float* bias  = (const float*)d_in[5];
    float* out = (float*)d_out;

    // workspace layout (~20.05 MB)
    unsigned int* h_bf = (unsigned int*)d_ws;                   // 12.8 MB
    float* asrc = (float*)(h_bf + (size_t)N_NODES * 64);        // 1.6 MB
    float* adst = asrc + (size_t)N_NODES * HEADS;               // 1.6 MB
    unsigned int* bin = (unsigned int*)(adst + (size_t)N_NODES * HEADS); // 4.0 MB
    unsigned int* wfrag = bin + (size_t)NBUCK * BCAP;           // 40 KB (16B-aligned)
    int* cnt = (int*)(wfrag + 10240);                           // 782 ints

    hipMemsetAsync(cnt, 0, NBUCK * sizeof(int), stream);
    k_prepW<<<4, 512, 0, stream>>>(W, att_s, att_d, wfrag);
    k_fused<<<BINB + GEMMB, 512, 0, stream>>>(x, wfrag, ei,
                                              h_bf, asrc, adst, cnt, bin);
    k_aggr<<<NBUCK, 512, 0, stream>>>(h_bf, bin, cnt, asrc, adst, bias, out);
}